// Round 2
// baseline (7293.269 us; speedup 1.0000x reference)
//
#include <hip/hip_runtime.h>
#include <math.h>

#define BB 64
#define NN 512
#define KK 16

// ---------------------------------------------------------------------------
// GELU helpers
// ---------------------------------------------------------------------------
__device__ __forceinline__ float gelu32(float x) {
    return 0.5f * x * (1.0f + erff(x * 0.70710678118654752440f));
}

// Table-based f64 GELU: erf(z) via nearest-node cubic Taylor, h = 1/128.
// abs error <= ~5e-11; tail cutoff |x| >= 7.4 (erfc(5.23) ~ 1.4e-13).
#define TAB_N 672
__device__ __forceinline__ double gelu64_tab(double x, const double2* s_tab) {
    double ax = fabs(x);
    if (ax >= 7.4) return x > 0.0 ? x : 0.0;
    double z = ax * 0.70710678118654752440;
    double u = z * 128.0;
    int i = (int)(u + 0.5);
    double zi = (double)i * (1.0 / 128.0);
    double d = z - zi;
    double2 t = s_tab[i];
    // erf(zi + d) = E + G*(d - zi*d^2 + (2*zi^2-1)/3 * d^3)
    double poly = d * (1.0 + d * (-zi + d * ((2.0 * zi * zi - 1.0) * (1.0 / 3.0))));
    double er = t.x + t.y * poly;
    double s = (x > 0.0) ? er : -er;
    return 0.5 * x * (1.0 + s);
}

__global__ void build_tab(double2* __restrict__ g_tab) {
    for (int i = threadIdx.x; i < TAB_N; i += 256) {
        double z = (double)i * (1.0 / 128.0);
        double2 e;
        e.x = erf(z);
        e.y = 1.12837916709551257390 * exp(-z * z);  // 2/sqrt(pi) * exp(-z^2)
        g_tab[i] = e;
    }
}

// ---------------------------------------------------------------------------
// Block-1 kNN: F=3 points (+999 mask shift), f64, top-17 drop-first.
// 4 queries per 256-thread block (one wave per query); shared staged points.
// ---------------------------------------------------------------------------
__global__ __launch_bounds__(256, 4) void knn1(const float* __restrict__ points,
                                               const int* __restrict__ mask,
                                               int* __restrict__ idx_out) {
    __shared__ double pts[3][NN];    // transposed: 2-way bank alias (free)
    __shared__ double dist[4][NN];
    const int b = blockIdx.x >> 7;          // 128 blocks per batch
    const int n0 = (blockIdx.x & 127) * 4;
    const int tid = threadIdx.x;
    const int w = tid >> 6, lane = tid & 63;

    for (int e = tid; e < NN; e += 256) {
        double sh = (mask[b * NN + e] == 0) ? 999.0 : 0.0;
        const float* p = points + ((size_t)b * NN + e) * 3;
        pts[0][e] = (double)p[0] + sh;
        pts[1][e] = (double)p[1] + sh;
        pts[2][e] = (double)p[2] + sh;
    }
    __syncthreads();

    const int n = n0 + w;
    const double q0 = pts[0][n], q1 = pts[1][n], q2 = pts[2][n];
    for (int i = 0; i < 8; ++i) {
        int m = lane + 64 * i;
        double d0 = q0 - pts[0][m], d1 = q1 - pts[1][m], d2 = q2 - pts[2][m];
        dist[w][m] = d0 * d0 + d1 * d1 + d2 * d2;   // +1e-5 const: ordering-invariant
    }
    __syncthreads();

    for (int it = 0; it <= KK; ++it) {
        double bd = 1e300;
        int bi = NN;
        for (int i = 0; i < 8; ++i) {
            int m = lane + 64 * i;              // ascending: strict < keeps lowest index
            double d = dist[w][m];
            if (d < bd) { bd = d; bi = m; }
        }
        for (int off = 32; off > 0; off >>= 1) {
            double od = __shfl_xor(bd, off, 64);
            int    oi = __shfl_xor(bi, off, 64);
            if (od < bd || (od == bd && oi < bi)) { bd = od; bi = oi; }
        }
        if (lane == 0) {
            dist[w][bi] = 1e300;
            if (it > 0) idx_out[(size_t)(b * NN + n) * KK + (it - 1)] = bi;
        }
        __syncthreads();
    }
}

// ---------------------------------------------------------------------------
// Block-1 MLP in f64 (table GELU). One 256-thread block per (b, n).
// ---------------------------------------------------------------------------
__global__ __launch_bounds__(256, 4) void mlp1_f64(const float* __restrict__ x,
                                                   const int* __restrict__ idx,
                                                   const float* __restrict__ W1,
                                                   const float* __restrict__ b1,
                                                   const float* __restrict__ W2,
                                                   const float* __restrict__ b2,
                                                   const double2* __restrict__ g_tab,
                                                   double* __restrict__ feats_out) {
    const int C = 32;
    __shared__ double2 s_tab[TAB_N];   // 10.5 KB
    __shared__ double ctr[32];
    __shared__ double edg[KK][32];
    __shared__ double H1[KK][128];
    __shared__ double H2s[KK][64];
    const int swz = ((blockIdx.x & 7) << 12) + (blockIdx.x >> 3);  // 32768/8 = 4096
    const int b = swz >> 9;
    const int bn = swz;
    const int tid = threadIdx.x;

    for (int i = tid; i < TAB_N; i += 256) s_tab[i] = g_tab[i];
    if (tid < C) ctr[tid] = (double)x[(size_t)bn * C + tid];
    __syncthreads();
    for (int e = tid; e < KK * C; e += 256) {
        int k = e >> 5, c = e & 31;
        int m = idx[bn * KK + k];
        edg[k][c] = (double)x[((size_t)b * NN + m) * C + c] - ctr[c];
    }
    __syncthreads();

    {   // layer 1: H1[k][j]
        const int j = tid & 127;
        const int kb = (tid >> 7) * 8;
        double cterm = (double)b1[j];
        for (int c = 0; c < C; ++c) cterm += ctr[c] * (double)W1[(C + c) * 128 + j];
        double acc[8];
        #pragma unroll
        for (int kk = 0; kk < 8; ++kk) acc[kk] = cterm;
        for (int c = 0; c < C; ++c) {
            double w = (double)W1[c * 128 + j];
            #pragma unroll
            for (int kk = 0; kk < 8; ++kk) acc[kk] += edg[kb + kk][c] * w;
        }
        #pragma unroll
        for (int kk = 0; kk < 8; ++kk) H1[kb + kk][j] = gelu64_tab(acc[kk], s_tab);
    }
    __syncthreads();

    {   // layer 2: H2[k][j]
        const int j = tid & 63;
        const int kb = (tid >> 6) * 4;
        double acc[4];
        #pragma unroll
        for (int kk = 0; kk < 4; ++kk) acc[kk] = (double)b2[j];
        for (int c = 0; c < 128; ++c) {
            double w = (double)W2[c * 64 + j];
            #pragma unroll
            for (int kk = 0; kk < 4; ++kk) acc[kk] += H1[kb + kk][c] * w;
        }
        #pragma unroll
        for (int kk = 0; kk < 4; ++kk) H2s[kb + kk][j] = gelu64_tab(acc[kk], s_tab);
    }
    __syncthreads();

    if (tid < 64) {
        double s = 0.0;
        for (int k = 0; k < KK; ++k) s += H2s[k][tid];
        feats_out[(size_t)bn * 64 + tid] = s * 0.0625;
    }
}

// ---------------------------------------------------------------------------
// Per-row precompute for knn2: rm_sh = sum((f+sh)^2), Sq = sum(f+sh).
// One wave per row.
// ---------------------------------------------------------------------------
__global__ __launch_bounds__(256) void rms_pre(const double* __restrict__ feats,
                                               const int* __restrict__ mask,
                                               double* __restrict__ rm,
                                               double* __restrict__ Sq) {
    const int tid = threadIdx.x;
    const int row = blockIdx.x * 4 + (tid >> 6);
    const int lane = tid & 63;
    double sh = (mask[row] == 0) ? 999.0 : 0.0;
    double v = feats[(size_t)row * 64 + lane] + sh;
    double s2 = v * v, s1 = v;
    for (int off = 32; off > 0; off >>= 1) {
        s2 += __shfl_xor(s2, off, 64);
        s1 += __shfl_xor(s1, off, 64);
    }
    if (lane == 0) { rm[row] = s2; Sq[row] = s1; }
}

// ---------------------------------------------------------------------------
// Block-2 kNN: F=64 f64 feats, top-17 drop-first.
// 4 queries per 256-thread block; LDS-staged 64-candidate tiles (padded,
// transposed); rm/Sq hoisted; XCD-swizzled for L2 residency.
// ---------------------------------------------------------------------------
__global__ __launch_bounds__(256) void knn2(const double* __restrict__ feats,
                                            const int* __restrict__ mask,
                                            const double* __restrict__ rm,
                                            const double* __restrict__ Sq,
                                            int* __restrict__ idx_out) {
    __shared__ double tileT[64][65];   // [f][c], pad -> 2-way alias (free)
    __shared__ double dist[4][NN];
    __shared__ double qsh[4][64];
    __shared__ double qrn[4], qSq[4];
    const int bid = ((blockIdx.x & 7) << 10) + (blockIdx.x >> 3);  // 8192/8 = 1024
    const int b = bid >> 7;
    const int n0 = (bid & 127) * 4;
    const int tid = threadIdx.x;
    const int w = tid >> 6, lane = tid & 63;
    const int n = n0 + w;

    {
        double sh = (mask[b * NN + n] == 0) ? 999.0 : 0.0;
        qsh[w][lane] = feats[(size_t)(b * NN + n) * 64 + lane] + sh;
        if (lane == 0) { qrn[w] = rm[b * NN + n]; qSq[w] = Sq[b * NN + n]; }
    }
    __syncthreads();

    for (int t = 0; t < 8; ++t) {
        #pragma unroll
        for (int i = 0; i < 16; ++i) {
            int e = tid + 256 * i;
            int f = e & 63, c = e >> 6;
            tileT[f][c] = feats[(size_t)(b * NN + t * 64 + c) * 64 + f];
        }
        __syncthreads();
        int m = t * 64 + lane;
        double sh_m = (mask[b * NN + m] == 0) ? 999.0 : 0.0;
        double a0 = 0.0, a1 = 0.0, a2 = 0.0, a3 = 0.0;
        for (int f = 0; f < 64; f += 4) {
            a0 += qsh[w][f + 0] * tileT[f + 0][lane];
            a1 += qsh[w][f + 1] * tileT[f + 1][lane];
            a2 += qsh[w][f + 2] * tileT[f + 2][lane];
            a3 += qsh[w][f + 3] * tileT[f + 3][lane];
        }
        double dot = (a0 + a1) + (a2 + a3);
        dist[w][m] = qrn[w] + rm[b * NN + m] - 2.0 * (dot + sh_m * qSq[w]) + 1e-5;
        __syncthreads();
    }

    for (int it = 0; it <= KK; ++it) {
        double bd = 1e300;
        int bi = NN;
        for (int i = 0; i < 8; ++i) {
            int m = lane + 64 * i;
            double d = dist[w][m];
            if (d < bd) { bd = d; bi = m; }
        }
        for (int off = 32; off > 0; off >>= 1) {
            double od = __shfl_xor(bd, off, 64);
            int    oi = __shfl_xor(bi, off, 64);
            if (od < bd || (od == bd && oi < bi)) { bd = od; bi = oi; }
        }
        if (lane == 0) {
            dist[w][bi] = 1e300;
            if (it > 0) idx_out[(size_t)(b * NN + n) * KK + (it - 1)] = bi;
        }
        __syncthreads();
    }
}

// ---------------------------------------------------------------------------
// Block-2 MLP in f32 + mean + final mask. One 256-thread block per (b, n).
// ---------------------------------------------------------------------------
__global__ __launch_bounds__(256) void mlp2_f32(const double* __restrict__ feats,
                                                const int* __restrict__ idx,
                                                const float* __restrict__ W1,
                                                const float* __restrict__ b1,
                                                const float* __restrict__ W2,
                                                const float* __restrict__ b2,
                                                const int* __restrict__ mask,
                                                float* __restrict__ out) {
    const int C = 64;
    __shared__ float ctr[64];
    __shared__ float edg[KK][64];
    __shared__ float H1[KK][128];
    __shared__ float H2s[KK][64];
    const int swz = ((blockIdx.x & 7) << 12) + (blockIdx.x >> 3);
    const int b = swz >> 9;
    const int bn = swz;
    const int tid = threadIdx.x;

    if (tid < C) ctr[tid] = (float)feats[(size_t)bn * C + tid];
    __syncthreads();
    for (int e = tid; e < KK * C; e += 256) {
        int k = e >> 6, c = e & 63;
        int m = idx[bn * KK + k];
        edg[k][c] = (float)feats[((size_t)b * NN + m) * C + c] - ctr[c];
    }
    __syncthreads();

    {   // layer 1
        const int j = tid & 127;
        const int kb = (tid >> 7) * 8;
        float cterm = b1[j];
        for (int c = 0; c < C; ++c) cterm += ctr[c] * W1[(C + c) * 128 + j];
        float acc[8];
        #pragma unroll
        for (int kk = 0; kk < 8; ++kk) acc[kk] = cterm;
        for (int c = 0; c < C; ++c) {
            float w = W1[c * 128 + j];
            #pragma unroll
            for (int kk = 0; kk < 8; ++kk) acc[kk] += edg[kb + kk][c] * w;
        }
        #pragma unroll
        for (int kk = 0; kk < 8; ++kk) H1[kb + kk][j] = gelu32(acc[kk]);
    }
    __syncthreads();

    {   // layer 2
        const int j = tid & 63;
        const int kb = (tid >> 6) * 4;
        float acc[4];
        #pragma unroll
        for (int kk = 0; kk < 4; ++kk) acc[kk] = b2[j];
        for (int c = 0; c < 128; ++c) {
            float w = W2[c * 64 + j];
            #pragma unroll
            for (int kk = 0; kk < 4; ++kk) acc[kk] += H1[kb + kk][c] * w;
        }
        #pragma unroll
        for (int kk = 0; kk < 4; ++kk) H2s[kb + kk][j] = gelu32(acc[kk]);
    }
    __syncthreads();

    if (tid < 64) {
        float s = 0.0f;
        for (int k = 0; k < KK; ++k) s += H2s[k][tid];
        s *= 0.0625f;
        if (mask[bn] == 0) s = 0.0f;
        out[(size_t)bn * 64 + tid] = s;
    }
}

extern "C" void kernel_launch(void* const* d_in, const int* in_sizes, int n_in,
                              void* d_out, int out_size, void* d_ws, size_t ws_size,
                              hipStream_t stream) {
    const float* x      = (const float*)d_in[0];
    const float* points = (const float*)d_in[1];
    const int*   mask   = (const int*)d_in[2];
    const float* W1_0 = (const float*)d_in[3];
    const float* b1_0 = (const float*)d_in[4];
    const float* W2_0 = (const float*)d_in[5];
    const float* b2_0 = (const float*)d_in[6];
    const float* W1_1 = (const float*)d_in[7];
    const float* b1_1 = (const float*)d_in[8];
    const float* W2_1 = (const float*)d_in[9];
    const float* b2_1 = (const float*)d_in[10];

    char* ws = (char*)d_ws;
    double2* tab    = (double2*)ws;                       //   16 KB (672*16 used)
    int*     idx    = (int*)(ws + 16384);                 //    2 MB
    double*  feats1 = (double*)(ws + 16384 + 2097152);    // 16.8 MB
    double*  rm     = (double*)(ws + 16384 + 2097152 + 16777216);           // 256 KB
    double*  Sq     = (double*)(ws + 16384 + 2097152 + 16777216 + 262144);  // 256 KB

    build_tab<<<1, 256, 0, stream>>>(tab);
    knn1<<<BB * NN / 4, 256, 0, stream>>>(points, mask, idx);
    mlp1_f64<<<BB * NN, 256, 0, stream>>>(x, idx, W1_0, b1_0, W2_0, b2_0, tab, feats1);
    rms_pre<<<BB * NN / 4, 256, 0, stream>>>(feats1, mask, rm, Sq);
    knn2<<<BB * NN / 4, 256, 0, stream>>>(feats1, mask, rm, Sq, idx);
    mlp2_f32<<<BB * NN, 256, 0, stream>>>(feats1, idx, W1_1, b1_1, W2_1, b2_1, mask, (float*)d_out);
}

// Round 3
// 4313.081 us; speedup vs baseline: 1.6910x; 1.6910x over previous
//
#include <hip/hip_runtime.h>
#include <math.h>

#define BB 64
#define NN 512
#define KK 16

// ---------------------------------------------------------------------------
// GELU helpers
// ---------------------------------------------------------------------------
__device__ __forceinline__ float gelu32(float x) {
    return 0.5f * x * (1.0f + erff(x * 0.70710678118654752440f));
}

// Table-based f64 GELU: erf(z) via nearest-node cubic Taylor, h = 1/128.
// abs error <= ~5e-11; tail cutoff |x| >= 7.4 (erfc(5.23) ~ 1.4e-13).
#define TAB_N 672
__device__ __forceinline__ double gelu64_tab(double x, const double2* s_tab) {
    double ax = fabs(x);
    if (ax >= 7.4) return x > 0.0 ? x : 0.0;
    double z = ax * 0.70710678118654752440;
    double u = z * 128.0;
    int i = (int)(u + 0.5);
    double zi = (double)i * (1.0 / 128.0);
    double d = z - zi;
    double2 t = s_tab[i];
    // erf(zi + d) = E + G*(d - zi*d^2 + (2*zi^2-1)/3 * d^3)
    double poly = d * (1.0 + d * (-zi + d * ((2.0 * zi * zi - 1.0) * (1.0 / 3.0))));
    double er = t.x + t.y * poly;
    double s = (x > 0.0) ? er : -er;
    return 0.5 * x * (1.0 + s);
}

__global__ void build_tab(double2* __restrict__ g_tab) {
    for (int i = threadIdx.x; i < TAB_N; i += 256) {
        double z = (double)i * (1.0 / 128.0);
        double2 e;
        e.x = erf(z);
        e.y = 1.12837916709551257390 * exp(-z * z);  // 2/sqrt(pi) * exp(-z^2)
        g_tab[i] = e;
    }
}

// ---------------------------------------------------------------------------
// Block-1 kNN: F=3 points (+999 mask shift), f64, top-17 drop-first.
// 4 queries per 256-thread block (one wave per query); shared staged points.
// ---------------------------------------------------------------------------
__global__ __launch_bounds__(256, 4) void knn1(const float* __restrict__ points,
                                               const int* __restrict__ mask,
                                               int* __restrict__ idx_out) {
    __shared__ double pts[3][NN];    // transposed: 2-way bank alias (free)
    __shared__ double dist[4][NN];
    const int b = blockIdx.x >> 7;          // 128 blocks per batch
    const int n0 = (blockIdx.x & 127) * 4;
    const int tid = threadIdx.x;
    const int w = tid >> 6, lane = tid & 63;

    for (int e = tid; e < NN; e += 256) {
        double sh = (mask[b * NN + e] == 0) ? 999.0 : 0.0;
        const float* p = points + ((size_t)b * NN + e) * 3;
        pts[0][e] = (double)p[0] + sh;
        pts[1][e] = (double)p[1] + sh;
        pts[2][e] = (double)p[2] + sh;
    }
    __syncthreads();

    const int n = n0 + w;
    const double q0 = pts[0][n], q1 = pts[1][n], q2 = pts[2][n];
    for (int i = 0; i < 8; ++i) {
        int m = lane + 64 * i;
        double d0 = q0 - pts[0][m], d1 = q1 - pts[1][m], d2 = q2 - pts[2][m];
        dist[w][m] = d0 * d0 + d1 * d1 + d2 * d2;   // +1e-5 const: ordering-invariant
    }
    __syncthreads();

    for (int it = 0; it <= KK; ++it) {
        double bd = 1e300;
        int bi = NN;
        for (int i = 0; i < 8; ++i) {
            int m = lane + 64 * i;              // ascending: strict < keeps lowest index
            double d = dist[w][m];
            if (d < bd) { bd = d; bi = m; }
        }
        for (int off = 32; off > 0; off >>= 1) {
            double od = __shfl_xor(bd, off, 64);
            int    oi = __shfl_xor(bi, off, 64);
            if (od < bd || (od == bd && oi < bi)) { bd = od; bi = oi; }
        }
        if (lane == 0) {
            dist[w][bi] = 1e300;
            if (it > 0) idx_out[(size_t)(b * NN + n) * KK + (it - 1)] = bi;
        }
        __syncthreads();
    }
}

// ---------------------------------------------------------------------------
// Block-1 MLP in f64 (table GELU). One 256-thread block per (b, n).
// __launch_bounds__(256,2): empirically arg=4 caps VGPR at 64 -> catastrophic
// scratch spill (13 GB writes/dispatch, round 2); arg=2 caps at 128 which
// fits the ~100-VGPR natural need. LDS 33.5 KB -> 4 blocks/CU.
// ---------------------------------------------------------------------------
__global__ __launch_bounds__(256, 2) void mlp1_f64(const float* __restrict__ x,
                                                   const int* __restrict__ idx,
                                                   const float* __restrict__ W1,
                                                   const float* __restrict__ b1,
                                                   const float* __restrict__ W2,
                                                   const float* __restrict__ b2,
                                                   const double2* __restrict__ g_tab,
                                                   double* __restrict__ feats_out) {
    const int C = 32;
    __shared__ double2 s_tab[TAB_N];   // 10.5 KB
    __shared__ double ctr[32];
    __shared__ double edg[KK][32];     //  4 KB
    __shared__ double H1[KK][128];     // 16 KB
    __shared__ double part[4][64];     //  2 KB
    const int swz = ((blockIdx.x & 7) << 12) + (blockIdx.x >> 3);  // 32768/8 = 4096
    const int b = swz >> 9;
    const int bn = swz;
    const int tid = threadIdx.x;

    for (int i = tid; i < TAB_N; i += 256) s_tab[i] = g_tab[i];
    if (tid < C) ctr[tid] = (double)x[(size_t)bn * C + tid];
    __syncthreads();
    for (int e = tid; e < KK * C; e += 256) {
        int k = e >> 5, c = e & 31;
        int m = idx[bn * KK + k];
        edg[k][c] = (double)x[((size_t)b * NN + m) * C + c] - ctr[c];
    }
    __syncthreads();

    {   // layer 1: H1[k][j], thread -> (j = tid&127, k-block of 8)
        const int j = tid & 127;
        const int kb = (tid >> 7) * 8;
        double cterm = (double)b1[j];
        for (int c = 0; c < C; ++c) cterm += ctr[c] * (double)W1[(C + c) * 128 + j];
        double acc[8];
        #pragma unroll
        for (int kk = 0; kk < 8; ++kk) acc[kk] = cterm;
        for (int c = 0; c < C; ++c) {
            double w = (double)W1[c * 128 + j];
            #pragma unroll
            for (int kk = 0; kk < 8; ++kk) acc[kk] += edg[kb + kk][c] * w;
        }
        #pragma unroll
        for (int kk = 0; kk < 8; ++kk) H1[kb + kk][j] = gelu64_tab(acc[kk], s_tab);
    }
    __syncthreads();

    {   // layer 2: thread -> (j = tid&63, k-group g = tid>>6 of 4);
        // each thread sums its own 4 GELU outputs -> part[g][j]
        const int j = tid & 63;
        const int g = tid >> 6;
        const int kb = g * 4;
        double acc[4];
        #pragma unroll
        for (int kk = 0; kk < 4; ++kk) acc[kk] = (double)b2[j];
        for (int c = 0; c < 128; ++c) {
            double w = (double)W2[c * 64 + j];
            #pragma unroll
            for (int kk = 0; kk < 4; ++kk) acc[kk] += H1[kb + kk][c] * w;
        }
        double s = 0.0;
        #pragma unroll
        for (int kk = 0; kk < 4; ++kk) s += gelu64_tab(acc[kk], s_tab);
        part[g][j] = s;
    }
    __syncthreads();

    if (tid < 64) {
        double s = part[0][tid] + part[1][tid] + part[2][tid] + part[3][tid];
        feats_out[(size_t)bn * 64 + tid] = s * 0.0625;
    }
}

// ---------------------------------------------------------------------------
// Per-row precompute for knn2: rm_sh = sum((f+sh)^2), Sq = sum(f+sh).
// ---------------------------------------------------------------------------
__global__ __launch_bounds__(256) void rms_pre(const double* __restrict__ feats,
                                               const int* __restrict__ mask,
                                               double* __restrict__ rm,
                                               double* __restrict__ Sq) {
    const int tid = threadIdx.x;
    const int row = blockIdx.x * 4 + (tid >> 6);
    const int lane = tid & 63;
    double sh = (mask[row] == 0) ? 999.0 : 0.0;
    double v = feats[(size_t)row * 64 + lane] + sh;
    double s2 = v * v, s1 = v;
    for (int off = 32; off > 0; off >>= 1) {
        s2 += __shfl_xor(s2, off, 64);
        s1 += __shfl_xor(s1, off, 64);
    }
    if (lane == 0) { rm[row] = s2; Sq[row] = s1; }
}

// ---------------------------------------------------------------------------
// Block-2 kNN: F=64 f64 feats, top-17 drop-first.
// 4 queries per 256-thread block; LDS-staged 64-candidate tiles (padded,
// transposed); rm/Sq hoisted; XCD-swizzled for L2 residency.
// ---------------------------------------------------------------------------
__global__ __launch_bounds__(256) void knn2(const double* __restrict__ feats,
                                            const int* __restrict__ mask,
                                            const double* __restrict__ rm,
                                            const double* __restrict__ Sq,
                                            int* __restrict__ idx_out) {
    __shared__ double tileT[64][65];   // [f][c], pad -> 2-way alias (free)
    __shared__ double dist[4][NN];
    __shared__ double qsh[4][64];
    __shared__ double qrn[4], qSq[4];
    const int bid = ((blockIdx.x & 7) << 10) + (blockIdx.x >> 3);  // 8192/8 = 1024
    const int b = bid >> 7;
    const int n0 = (bid & 127) * 4;
    const int tid = threadIdx.x;
    const int w = tid >> 6, lane = tid & 63;
    const int n = n0 + w;

    {
        double sh = (mask[b * NN + n] == 0) ? 999.0 : 0.0;
        qsh[w][lane] = feats[(size_t)(b * NN + n) * 64 + lane] + sh;
        if (lane == 0) { qrn[w] = rm[b * NN + n]; qSq[w] = Sq[b * NN + n]; }
    }
    __syncthreads();

    for (int t = 0; t < 8; ++t) {
        #pragma unroll
        for (int i = 0; i < 16; ++i) {
            int e = tid + 256 * i;
            int f = e & 63, c = e >> 6;
            tileT[f][c] = feats[(size_t)(b * NN + t * 64 + c) * 64 + f];
        }
        __syncthreads();
        int m = t * 64 + lane;
        double sh_m = (mask[b * NN + m] == 0) ? 999.0 : 0.0;
        double a0 = 0.0, a1 = 0.0, a2 = 0.0, a3 = 0.0;
        for (int f = 0; f < 64; f += 4) {
            a0 += qsh[w][f + 0] * tileT[f + 0][lane];
            a1 += qsh[w][f + 1] * tileT[f + 1][lane];
            a2 += qsh[w][f + 2] * tileT[f + 2][lane];
            a3 += qsh[w][f + 3] * tileT[f + 3][lane];
        }
        double dot = (a0 + a1) + (a2 + a3);
        dist[w][m] = qrn[w] + rm[b * NN + m] - 2.0 * (dot + sh_m * qSq[w]) + 1e-5;
        __syncthreads();
    }

    for (int it = 0; it <= KK; ++it) {
        double bd = 1e300;
        int bi = NN;
        for (int i = 0; i < 8; ++i) {
            int m = lane + 64 * i;
            double d = dist[w][m];
            if (d < bd) { bd = d; bi = m; }
        }
        for (int off = 32; off > 0; off >>= 1) {
            double od = __shfl_xor(bd, off, 64);
            int    oi = __shfl_xor(bi, off, 64);
            if (od < bd || (od == bd && oi < bi)) { bd = od; bi = oi; }
        }
        if (lane == 0) {
            dist[w][bi] = 1e300;
            if (it > 0) idx_out[(size_t)(b * NN + n) * KK + (it - 1)] = bi;
        }
        __syncthreads();
    }
}

// ---------------------------------------------------------------------------
// Block-2 MLP in f32 + mean + final mask. One 256-thread block per (b, n).
// ---------------------------------------------------------------------------
__global__ __launch_bounds__(256) void mlp2_f32(const double* __restrict__ feats,
                                                const int* __restrict__ idx,
                                                const float* __restrict__ W1,
                                                const float* __restrict__ b1,
                                                const float* __restrict__ W2,
                                                const float* __restrict__ b2,
                                                const int* __restrict__ mask,
                                                float* __restrict__ out) {
    const int C = 64;
    __shared__ float ctr[64];
    __shared__ float edg[KK][64];
    __shared__ float H1[KK][128];
    __shared__ float H2s[KK][64];
    const int swz = ((blockIdx.x & 7) << 12) + (blockIdx.x >> 3);
    const int b = swz >> 9;
    const int bn = swz;
    const int tid = threadIdx.x;

    if (tid < C) ctr[tid] = (float)feats[(size_t)bn * C + tid];
    __syncthreads();
    for (int e = tid; e < KK * C; e += 256) {
        int k = e >> 6, c = e & 63;
        int m = idx[bn * KK + k];
        edg[k][c] = (float)feats[((size_t)b * NN + m) * C + c] - ctr[c];
    }
    __syncthreads();

    {   // layer 1
        const int j = tid & 127;
        const int kb = (tid >> 7) * 8;
        float cterm = b1[j];
        for (int c = 0; c < C; ++c) cterm += ctr[c] * W1[(C + c) * 128 + j];
        float acc[8];
        #pragma unroll
        for (int kk = 0; kk < 8; ++kk) acc[kk] = cterm;
        for (int c = 0; c < C; ++c) {
            float w = W1[c * 128 + j];
            #pragma unroll
            for (int kk = 0; kk < 8; ++kk) acc[kk] += edg[kb + kk][c] * w;
        }
        #pragma unroll
        for (int kk = 0; kk < 8; ++kk) H1[kb + kk][j] = gelu32(acc[kk]);
    }
    __syncthreads();

    {   // layer 2
        const int j = tid & 63;
        const int kb = (tid >> 6) * 4;
        float acc[4];
        #pragma unroll
        for (int kk = 0; kk < 4; ++kk) acc[kk] = b2[j];
        for (int c = 0; c < 128; ++c) {
            float w = W2[c * 64 + j];
            #pragma unroll
            for (int kk = 0; kk < 4; ++kk) acc[kk] += H1[kb + kk][c] * w;
        }
        #pragma unroll
        for (int kk = 0; kk < 4; ++kk) H2s[kb + kk][j] = gelu32(acc[kk]);
    }
    __syncthreads();

    if (tid < 64) {
        float s = 0.0f;
        for (int k = 0; k < KK; ++k) s += H2s[k][tid];
        s *= 0.0625f;
        if (mask[bn] == 0) s = 0.0f;
        out[(size_t)bn * 64 + tid] = s;
    }
}

extern "C" void kernel_launch(void* const* d_in, const int* in_sizes, int n_in,
                              void* d_out, int out_size, void* d_ws, size_t ws_size,
                              hipStream_t stream) {
    const float* x      = (const float*)d_in[0];
    const float* points = (const float*)d_in[1];
    const int*   mask   = (const int*)d_in[2];
    const float* W1_0 = (const float*)d_in[3];
    const float* b1_0 = (const float*)d_in[4];
    const float* W2_0 = (const float*)d_in[5];
    const float* b2_0 = (const float*)d_in[6];
    const float* W1_1 = (const float*)d_in[7];
    const float* b1_1 = (const float*)d_in[8];
    const float* W2_1 = (const float*)d_in[9];
    const float* b2_1 = (const float*)d_in[10];

    char* ws = (char*)d_ws;
    double2* tab    = (double2*)ws;                       //   16 KB (672*16 used)
    int*     idx    = (int*)(ws + 16384);                 //    2 MB
    double*  feats1 = (double*)(ws + 16384 + 2097152);    // 16.8 MB
    double*  rm     = (double*)(ws + 16384 + 2097152 + 16777216);           // 256 KB
    double*  Sq     = (double*)(ws + 16384 + 2097152 + 16777216 + 262144);  // 256 KB

    build_tab<<<1, 256, 0, stream>>>(tab);
    knn1<<<BB * NN / 4, 256, 0, stream>>>(points, mask, idx);
    mlp1_f64<<<BB * NN, 256, 0, stream>>>(x, idx, W1_0, b1_0, W2_0, b2_0, tab, feats1);
    rms_pre<<<BB * NN / 4, 256, 0, stream>>>(feats1, mask, rm, Sq);
    knn2<<<BB * NN / 4, 256, 0, stream>>>(feats1, mask, rm, Sq, idx);
    mlp2_f32<<<BB * NN, 256, 0, stream>>>(feats1, idx, W1_1, b1_1, W2_1, b2_1, mask, (float*)d_out);
}

// Round 4
// 1588.929 us; speedup vs baseline: 4.5901x; 2.7145x over previous
//
#include <hip/hip_runtime.h>
#include <math.h>

#define BB 64
#define NN 512
#define KK 16

// ---------------------------------------------------------------------------
// GELU helpers
// ---------------------------------------------------------------------------
__device__ __forceinline__ float gelu32(float x) {
    return 0.5f * x * (1.0f + erff(x * 0.70710678118654752440f));
}

// Table-based f64 GELU: erf(z) via nearest-node cubic Taylor, h = 1/128.
// abs error <= ~5e-11; tail cutoff |x| >= 7.4 (erfc(5.23) ~ 1.4e-13).
#define TAB_N 672
__device__ __forceinline__ double gelu64_tab(double x, const double2* s_tab) {
    double ax = fabs(x);
    if (ax >= 7.4) return x > 0.0 ? x : 0.0;
    double z = ax * 0.70710678118654752440;
    double u = z * 128.0;
    int i = (int)(u + 0.5);
    double zi = (double)i * (1.0 / 128.0);
    double d = z - zi;
    double2 t = s_tab[i];
    // erf(zi + d) = E + G*(d - zi*d^2 + (2*zi^2-1)/3 * d^3)
    double poly = d * (1.0 + d * (-zi + d * ((2.0 * zi * zi - 1.0) * (1.0 / 3.0))));
    double er = t.x + t.y * poly;
    double s = (x > 0.0) ? er : -er;
    return 0.5 * x * (1.0 + s);
}

__global__ void build_tab(double2* __restrict__ g_tab) {
    for (int i = threadIdx.x; i < TAB_N; i += 256) {
        double z = (double)i * (1.0 / 128.0);
        double2 e;
        e.x = erf(z);
        e.y = 1.12837916709551257390 * exp(-z * z);  // 2/sqrt(pi) * exp(-z^2)
        g_tab[i] = e;
    }
}

// ---------------------------------------------------------------------------
// Block-1 kNN: F=3 points (+999 mask shift), f64, top-17 drop-first.
// 4 queries per 256-thread block (one wave per query); shared staged points.
// ---------------------------------------------------------------------------
__global__ __launch_bounds__(256, 4) void knn1(const float* __restrict__ points,
                                               const int* __restrict__ mask,
                                               int* __restrict__ idx_out) {
    __shared__ double pts[3][NN];    // transposed: 2-way bank alias (free)
    __shared__ double dist[4][NN];
    const int b = blockIdx.x >> 7;          // 128 blocks per batch
    const int n0 = (blockIdx.x & 127) * 4;
    const int tid = threadIdx.x;
    const int w = tid >> 6, lane = tid & 63;

    for (int e = tid; e < NN; e += 256) {
        double sh = (mask[b * NN + e] == 0) ? 999.0 : 0.0;
        const float* p = points + ((size_t)b * NN + e) * 3;
        pts[0][e] = (double)p[0] + sh;
        pts[1][e] = (double)p[1] + sh;
        pts[2][e] = (double)p[2] + sh;
    }
    __syncthreads();

    const int n = n0 + w;
    const double q0 = pts[0][n], q1 = pts[1][n], q2 = pts[2][n];
    for (int i = 0; i < 8; ++i) {
        int m = lane + 64 * i;
        double d0 = q0 - pts[0][m], d1 = q1 - pts[1][m], d2 = q2 - pts[2][m];
        dist[w][m] = d0 * d0 + d1 * d1 + d2 * d2;   // +1e-5 const: ordering-invariant
    }
    __syncthreads();

    for (int it = 0; it <= KK; ++it) {
        double bd = 1e300;
        int bi = NN;
        for (int i = 0; i < 8; ++i) {
            int m = lane + 64 * i;              // ascending: strict < keeps lowest index
            double d = dist[w][m];
            if (d < bd) { bd = d; bi = m; }
        }
        for (int off = 32; off > 0; off >>= 1) {
            double od = __shfl_xor(bd, off, 64);
            int    oi = __shfl_xor(bi, off, 64);
            if (od < bd || (od == bd && oi < bi)) { bd = od; bi = oi; }
        }
        if (lane == 0) {
            dist[w][bi] = 1e300;
            if (it > 0) idx_out[(size_t)(b * NN + n) * KK + (it - 1)] = bi;
        }
        __syncthreads();
    }
}

// ---------------------------------------------------------------------------
// Block-1 MLP in f64 (table GELU). One 256-thread block per (b, n).
// Register discipline: natural demand with fully-unrolled c-loops is ~200+
// VGPR (round 3: 9 GB scratch writes at cap 128). `#pragma unroll 2` bounds
// the live-value window (2 weight loads + FMA group per iter) so the kernel
// fits the (256,2) 128-VGPR cap without spilling.
// ---------------------------------------------------------------------------
__global__ __launch_bounds__(256, 2) void mlp1_f64(const float* __restrict__ x,
                                                   const int* __restrict__ idx,
                                                   const float* __restrict__ W1,
                                                   const float* __restrict__ b1,
                                                   const float* __restrict__ W2,
                                                   const float* __restrict__ b2,
                                                   const double2* __restrict__ g_tab,
                                                   double* __restrict__ feats_out) {
    const int C = 32;
    __shared__ double2 s_tab[TAB_N];   // 10.5 KB
    __shared__ double ctr[32];
    __shared__ double edg[KK][32];     //  4 KB
    __shared__ double H1[KK][128];     // 16 KB
    __shared__ double part[4][64];     //  2 KB
    const int swz = ((blockIdx.x & 7) << 12) + (blockIdx.x >> 3);  // 32768/8 = 4096
    const int b = swz >> 9;
    const int bn = swz;
    const int tid = threadIdx.x;

    for (int i = tid; i < TAB_N; i += 256) s_tab[i] = g_tab[i];
    if (tid < C) ctr[tid] = (double)x[(size_t)bn * C + tid];
    __syncthreads();
    for (int e = tid; e < KK * C; e += 256) {
        int k = e >> 5, c = e & 31;
        int m = idx[bn * KK + k];
        edg[k][c] = (double)x[((size_t)b * NN + m) * C + c] - ctr[c];
    }
    __syncthreads();

    {   // layer 1: H1[k][j], thread -> (j = tid&127, k-block of 8)
        const int j = tid & 127;
        const int kb = (tid >> 7) * 8;
        double cterm = (double)b1[j];
        #pragma unroll 2
        for (int c = 0; c < C; ++c) cterm += ctr[c] * (double)W1[(C + c) * 128 + j];
        double acc[8];
        #pragma unroll
        for (int kk = 0; kk < 8; ++kk) acc[kk] = cterm;
        #pragma unroll 2
        for (int c = 0; c < C; ++c) {
            double w = (double)W1[c * 128 + j];
            #pragma unroll
            for (int kk = 0; kk < 8; ++kk) acc[kk] += edg[kb + kk][c] * w;
        }
        #pragma unroll
        for (int kk = 0; kk < 8; ++kk) H1[kb + kk][j] = gelu64_tab(acc[kk], s_tab);
    }
    __syncthreads();

    {   // layer 2: thread -> (j = tid&63, k-group g = tid>>6 of 4);
        // each thread sums its own 4 GELU outputs -> part[g][j]
        const int j = tid & 63;
        const int g = tid >> 6;
        const int kb = g * 4;
        double acc[4];
        #pragma unroll
        for (int kk = 0; kk < 4; ++kk) acc[kk] = (double)b2[j];
        #pragma unroll 2
        for (int c = 0; c < 128; ++c) {
            double w = (double)W2[c * 64 + j];
            #pragma unroll
            for (int kk = 0; kk < 4; ++kk) acc[kk] += H1[kb + kk][c] * w;
        }
        double s = 0.0;
        #pragma unroll
        for (int kk = 0; kk < 4; ++kk) s += gelu64_tab(acc[kk], s_tab);
        part[g][j] = s;
    }
    __syncthreads();

    if (tid < 64) {
        double s = part[0][tid] + part[1][tid] + part[2][tid] + part[3][tid];
        feats_out[(size_t)bn * 64 + tid] = s * 0.0625;
    }
}

// ---------------------------------------------------------------------------
// Per-row precompute for knn2: rm_sh = sum((f+sh)^2), Sq = sum(f+sh).
// ---------------------------------------------------------------------------
__global__ __launch_bounds__(256) void rms_pre(const double* __restrict__ feats,
                                               const int* __restrict__ mask,
                                               double* __restrict__ rm,
                                               double* __restrict__ Sq) {
    const int tid = threadIdx.x;
    const int row = blockIdx.x * 4 + (tid >> 6);
    const int lane = tid & 63;
    double sh = (mask[row] == 0) ? 999.0 : 0.0;
    double v = feats[(size_t)row * 64 + lane] + sh;
    double s2 = v * v, s1 = v;
    for (int off = 32; off > 0; off >>= 1) {
        s2 += __shfl_xor(s2, off, 64);
        s1 += __shfl_xor(s1, off, 64);
    }
    if (lane == 0) { rm[row] = s2; Sq[row] = s1; }
}

// ---------------------------------------------------------------------------
// Block-2 kNN: F=64 f64 feats, top-17 drop-first.
// 4 queries per 256-thread block; LDS-staged 64-candidate tiles (padded,
// transposed); rm/Sq hoisted; XCD-swizzled for L2 residency.
// ---------------------------------------------------------------------------
__global__ __launch_bounds__(256) void knn2(const double* __restrict__ feats,
                                            const int* __restrict__ mask,
                                            const double* __restrict__ rm,
                                            const double* __restrict__ Sq,
                                            int* __restrict__ idx_out) {
    __shared__ double tileT[64][65];   // [f][c], pad -> 2-way alias (free)
    __shared__ double dist[4][NN];
    __shared__ double qsh[4][64];
    __shared__ double qrn[4], qSq[4];
    const int bid = ((blockIdx.x & 7) << 10) + (blockIdx.x >> 3);  // 8192/8 = 1024
    const int b = bid >> 7;
    const int n0 = (bid & 127) * 4;
    const int tid = threadIdx.x;
    const int w = tid >> 6, lane = tid & 63;
    const int n = n0 + w;

    {
        double sh = (mask[b * NN + n] == 0) ? 999.0 : 0.0;
        qsh[w][lane] = feats[(size_t)(b * NN + n) * 64 + lane] + sh;
        if (lane == 0) { qrn[w] = rm[b * NN + n]; qSq[w] = Sq[b * NN + n]; }
    }
    __syncthreads();

    for (int t = 0; t < 8; ++t) {
        #pragma unroll
        for (int i = 0; i < 16; ++i) {
            int e = tid + 256 * i;
            int f = e & 63, c = e >> 6;
            tileT[f][c] = feats[(size_t)(b * NN + t * 64 + c) * 64 + f];
        }
        __syncthreads();
        int m = t * 64 + lane;
        double sh_m = (mask[b * NN + m] == 0) ? 999.0 : 0.0;
        double a0 = 0.0, a1 = 0.0, a2 = 0.0, a3 = 0.0;
        for (int f = 0; f < 64; f += 4) {
            a0 += qsh[w][f + 0] * tileT[f + 0][lane];
            a1 += qsh[w][f + 1] * tileT[f + 1][lane];
            a2 += qsh[w][f + 2] * tileT[f + 2][lane];
            a3 += qsh[w][f + 3] * tileT[f + 3][lane];
        }
        double dot = (a0 + a1) + (a2 + a3);
        dist[w][m] = qrn[w] + rm[b * NN + m] - 2.0 * (dot + sh_m * qSq[w]) + 1e-5;
        __syncthreads();
    }

    for (int it = 0; it <= KK; ++it) {
        double bd = 1e300;
        int bi = NN;
        for (int i = 0; i < 8; ++i) {
            int m = lane + 64 * i;
            double d = dist[w][m];
            if (d < bd) { bd = d; bi = m; }
        }
        for (int off = 32; off > 0; off >>= 1) {
            double od = __shfl_xor(bd, off, 64);
            int    oi = __shfl_xor(bi, off, 64);
            if (od < bd || (od == bd && oi < bi)) { bd = od; bi = oi; }
        }
        if (lane == 0) {
            dist[w][bi] = 1e300;
            if (it > 0) idx_out[(size_t)(b * NN + n) * KK + (it - 1)] = bi;
        }
        __syncthreads();
    }
}

// ---------------------------------------------------------------------------
// Block-2 MLP in f32 + mean + final mask. One 256-thread block per (b, n).
// ---------------------------------------------------------------------------
__global__ __launch_bounds__(256) void mlp2_f32(const double* __restrict__ feats,
                                                const int* __restrict__ idx,
                                                const float* __restrict__ W1,
                                                const float* __restrict__ b1,
                                                const float* __restrict__ W2,
                                                const float* __restrict__ b2,
                                                const int* __restrict__ mask,
                                                float* __restrict__ out) {
    const int C = 64;
    __shared__ float ctr[64];
    __shared__ float edg[KK][64];
    __shared__ float H1[KK][128];
    __shared__ float H2s[KK][64];
    const int swz = ((blockIdx.x & 7) << 12) + (blockIdx.x >> 3);
    const int b = swz >> 9;
    const int bn = swz;
    const int tid = threadIdx.x;

    if (tid < C) ctr[tid] = (float)feats[(size_t)bn * C + tid];
    __syncthreads();
    for (int e = tid; e < KK * C; e += 256) {
        int k = e >> 6, c = e & 63;
        int m = idx[bn * KK + k];
        edg[k][c] = (float)feats[((size_t)b * NN + m) * C + c] - ctr[c];
    }
    __syncthreads();

    {   // layer 1
        const int j = tid & 127;
        const int kb = (tid >> 7) * 8;
        float cterm = b1[j];
        for (int c = 0; c < C; ++c) cterm += ctr[c] * W1[(C + c) * 128 + j];
        float acc[8];
        #pragma unroll
        for (int kk = 0; kk < 8; ++kk) acc[kk] = cterm;
        for (int c = 0; c < C; ++c) {
            float w = W1[c * 128 + j];
            #pragma unroll
            for (int kk = 0; kk < 8; ++kk) acc[kk] += edg[kb + kk][c] * w;
        }
        #pragma unroll
        for (int kk = 0; kk < 8; ++kk) H1[kb + kk][j] = gelu32(acc[kk]);
    }
    __syncthreads();

    {   // layer 2
        const int j = tid & 63;
        const int kb = (tid >> 6) * 4;
        float acc[4];
        #pragma unroll
        for (int kk = 0; kk < 4; ++kk) acc[kk] = b2[j];
        for (int c = 0; c < 128; ++c) {
            float w = W2[c * 64 + j];
            #pragma unroll
            for (int kk = 0; kk < 4; ++kk) acc[kk] += H1[kb + kk][c] * w;
        }
        #pragma unroll
        for (int kk = 0; kk < 4; ++kk) H2s[kb + kk][j] = gelu32(acc[kk]);
    }
    __syncthreads();

    if (tid < 64) {
        float s = 0.0f;
        for (int k = 0; k < KK; ++k) s += H2s[k][tid];
        s *= 0.0625f;
        if (mask[bn] == 0) s = 0.0f;
        out[(size_t)bn * 64 + tid] = s;
    }
}

extern "C" void kernel_launch(void* const* d_in, const int* in_sizes, int n_in,
                              void* d_out, int out_size, void* d_ws, size_t ws_size,
                              hipStream_t stream) {
    const float* x      = (const float*)d_in[0];
    const float* points = (const float*)d_in[1];
    const int*   mask   = (const int*)d_in[2];
    const float* W1_0 = (const float*)d_in[3];
    const float* b1_0 = (const float*)d_in[4];
    const float* W2_0 = (const float*)d_in[5];
    const float* b2_0 = (const float*)d_in[6];
    const float* W1_1 = (const float*)d_in[7];
    const float* b1_1 = (const float*)d_in[8];
    const float* W2_1 = (const float*)d_in[9];
    const float* b2_1 = (const float*)d_in[10];

    char* ws = (char*)d_ws;
    double2* tab    = (double2*)ws;                       //   16 KB (672*16 used)
    int*     idx    = (int*)(ws + 16384);                 //    2 MB
    double*  feats1 = (double*)(ws + 16384 + 2097152);    // 16.8 MB
    double*  rm     = (double*)(ws + 16384 + 2097152 + 16777216);           // 256 KB
    double*  Sq     = (double*)(ws + 16384 + 2097152 + 16777216 + 262144);  // 256 KB

    build_tab<<<1, 256, 0, stream>>>(tab);
    knn1<<<BB * NN / 4, 256, 0, stream>>>(points, mask, idx);
    mlp1_f64<<<BB * NN, 256, 0, stream>>>(x, idx, W1_0, b1_0, W2_0, b2_0, tab, feats1);
    rms_pre<<<BB * NN / 4, 256, 0, stream>>>(feats1, mask, rm, Sq);
    knn2<<<BB * NN / 4, 256, 0, stream>>>(feats1, mask, rm, Sq, idx);
    mlp2_f32<<<BB * NN, 256, 0, stream>>>(feats1, idx, W1_1, b1_1, W2_1, b2_1, mask, (float*)d_out);
}

// Round 5
// 1528.718 us; speedup vs baseline: 4.7708x; 1.0394x over previous
//
#include <hip/hip_runtime.h>
#include <math.h>

#define BB 64
#define NN 512
#define KK 16

// ---------------------------------------------------------------------------
// GELU helpers
// ---------------------------------------------------------------------------
__device__ __forceinline__ float gelu32(float x) {
    return 0.5f * x * (1.0f + erff(x * 0.70710678118654752440f));
}

// Table-based f64 GELU: erf(z) via nearest-node cubic Taylor, h = 1/128.
// abs error <= ~5e-11; tail cutoff |x| >= 7.4 (erfc(5.23) ~ 1.4e-13).
#define TAB_N 672
__device__ __forceinline__ double gelu64_tab(double x, const double2* s_tab) {
    double ax = fabs(x);
    if (ax >= 7.4) return x > 0.0 ? x : 0.0;
    double z = ax * 0.70710678118654752440;
    double u = z * 128.0;
    int i = (int)(u + 0.5);
    double zi = (double)i * (1.0 / 128.0);
    double d = z - zi;
    double2 t = s_tab[i];
    // erf(zi + d) = E + G*(d - zi*d^2 + (2*zi^2-1)/3 * d^3)
    double poly = d * (1.0 + d * (-zi + d * ((2.0 * zi * zi - 1.0) * (1.0 / 3.0))));
    double er = t.x + t.y * poly;
    double s = (x > 0.0) ? er : -er;
    return 0.5 * x * (1.0 + s);
}

__global__ void build_tab(double2* __restrict__ g_tab) {
    for (int i = threadIdx.x; i < TAB_N; i += 256) {
        double z = (double)i * (1.0 / 128.0);
        double2 e;
        e.x = erf(z);
        e.y = 1.12837916709551257390 * exp(-z * z);  // 2/sqrt(pi) * exp(-z^2)
        g_tab[i] = e;
    }
}

// ---------------------------------------------------------------------------
// Wave-local top-17 extraction from 8 register-resident candidates per lane.
// No LDS, no barriers. Tie-break: lexicographic (dist, index), identical to
// jax.lax.top_k on negated distances. Winner-removal uses compile-time
// indices only (runtime-indexed reg arrays go to scratch — rule #20).
// ---------------------------------------------------------------------------
#define SELECT_TOP17(d, lane, OUT_STMT)                                        \
    for (int it = 0; it <= KK; ++it) {                                         \
        double bd = d[0];                                                      \
        int bi = lane;                                                         \
        _Pragma("unroll")                                                      \
        for (int i = 1; i < 8; ++i) {                                          \
            int m = lane + 64 * i;                                             \
            if (d[i] < bd) { bd = d[i]; bi = m; }                              \
        }                                                                      \
        for (int off = 32; off > 0; off >>= 1) {                               \
            double od = __shfl_xor(bd, off, 64);                               \
            int    oi = __shfl_xor(bi, off, 64);                               \
            if (od < bd || (od == bd && oi < bi)) { bd = od; bi = oi; }        \
        }                                                                      \
        const int wl = bi & 63, wsl = bi >> 6;                                 \
        _Pragma("unroll")                                                      \
        for (int i = 0; i < 8; ++i)                                            \
            if (lane == wl && i == wsl) d[i] = 1e300;                          \
        if (it > 0 && lane == 0) { OUT_STMT; }                                 \
    }

// ---------------------------------------------------------------------------
// Block-1 kNN: F=3 points (+999 mask shift), f64, top-17 drop-first.
// 4 queries per 256-thread block; points staged in LDS; distances and the
// whole selection live in registers (barrier-free per wave).
// ---------------------------------------------------------------------------
__global__ __launch_bounds__(256, 4) void knn1(const float* __restrict__ points,
                                               const int* __restrict__ mask,
                                               int* __restrict__ idx_out) {
    __shared__ double pts[3][NN];    // transposed: 2-way bank alias (free)
    const int b = blockIdx.x >> 7;          // 128 blocks per batch
    const int n0 = (blockIdx.x & 127) * 4;
    const int tid = threadIdx.x;
    const int w = tid >> 6, lane = tid & 63;

    for (int e = tid; e < NN; e += 256) {
        double sh = (mask[b * NN + e] == 0) ? 999.0 : 0.0;
        const float* p = points + ((size_t)b * NN + e) * 3;
        pts[0][e] = (double)p[0] + sh;
        pts[1][e] = (double)p[1] + sh;
        pts[2][e] = (double)p[2] + sh;
    }
    __syncthreads();

    const int n = n0 + w;
    const double q0 = pts[0][n], q1 = pts[1][n], q2 = pts[2][n];
    double d[8];
    #pragma unroll
    for (int i = 0; i < 8; ++i) {
        int m = lane + 64 * i;
        double d0 = q0 - pts[0][m], d1 = q1 - pts[1][m], d2 = q2 - pts[2][m];
        d[i] = d0 * d0 + d1 * d1 + d2 * d2;   // +1e-5 const: ordering-invariant
    }

    int* orow = idx_out + (size_t)(b * NN + n) * KK;
    SELECT_TOP17(d, lane, orow[it - 1] = bi)
}

// ---------------------------------------------------------------------------
// Block-1 MLP in f64 (table GELU) + fused rm/Sq precompute for knn2.
// Register discipline: `#pragma unroll 2` bounds the live-value window so the
// kernel fits the (256,2) 128-VGPR cap without spilling (round 3: full unroll
// -> 9 GB scratch; round 4: VGPR=52, no spill, 657 us).
// ---------------------------------------------------------------------------
__global__ __launch_bounds__(256, 2) void mlp1_f64(const float* __restrict__ x,
                                                   const int* __restrict__ idx,
                                                   const float* __restrict__ W1,
                                                   const float* __restrict__ b1,
                                                   const float* __restrict__ W2,
                                                   const float* __restrict__ b2,
                                                   const double2* __restrict__ g_tab,
                                                   const int* __restrict__ mask,
                                                   double* __restrict__ feats_out,
                                                   double* __restrict__ rm,
                                                   double* __restrict__ Sq) {
    const int C = 32;
    __shared__ double2 s_tab[TAB_N];   // 10.5 KB
    __shared__ double ctr[32];
    __shared__ double edg[KK][32];     //  4 KB
    __shared__ double H1[KK][128];     // 16 KB
    __shared__ double part[4][64];     //  2 KB
    const int swz = ((blockIdx.x & 7) << 12) + (blockIdx.x >> 3);  // 32768/8 = 4096
    const int b = swz >> 9;
    const int bn = swz;
    const int tid = threadIdx.x;

    for (int i = tid; i < TAB_N; i += 256) s_tab[i] = g_tab[i];
    if (tid < C) ctr[tid] = (double)x[(size_t)bn * C + tid];
    __syncthreads();
    for (int e = tid; e < KK * C; e += 256) {
        int k = e >> 5, c = e & 31;
        int m = idx[bn * KK + k];
        edg[k][c] = (double)x[((size_t)b * NN + m) * C + c] - ctr[c];
    }
    __syncthreads();

    {   // layer 1: H1[k][j], thread -> (j = tid&127, k-block of 8)
        const int j = tid & 127;
        const int kb = (tid >> 7) * 8;
        double cterm = (double)b1[j];
        #pragma unroll 2
        for (int c = 0; c < C; ++c) cterm += ctr[c] * (double)W1[(C + c) * 128 + j];
        double acc[8];
        #pragma unroll
        for (int kk = 0; kk < 8; ++kk) acc[kk] = cterm;
        #pragma unroll 2
        for (int c = 0; c < C; ++c) {
            double w = (double)W1[c * 128 + j];
            #pragma unroll
            for (int kk = 0; kk < 8; ++kk) acc[kk] += edg[kb + kk][c] * w;
        }
        #pragma unroll
        for (int kk = 0; kk < 8; ++kk) H1[kb + kk][j] = gelu64_tab(acc[kk], s_tab);
    }
    __syncthreads();

    {   // layer 2: thread -> (j = tid&63, k-group g = tid>>6 of 4);
        // each thread sums its own 4 GELU outputs -> part[g][j]
        const int j = tid & 63;
        const int g = tid >> 6;
        const int kb = g * 4;
        double acc[4];
        #pragma unroll
        for (int kk = 0; kk < 4; ++kk) acc[kk] = (double)b2[j];
        #pragma unroll 2
        for (int c = 0; c < 128; ++c) {
            double w = (double)W2[c * 64 + j];
            #pragma unroll
            for (int kk = 0; kk < 4; ++kk) acc[kk] += H1[kb + kk][c] * w;
        }
        double s = 0.0;
        #pragma unroll
        for (int kk = 0; kk < 4; ++kk) s += gelu64_tab(acc[kk], s_tab);
        part[g][j] = s;
    }
    __syncthreads();

    if (tid < 64) {   // wave 0 exactly: epilogue + fused rm/Sq reduction
        double s = (part[0][tid] + part[1][tid] + part[2][tid] + part[3][tid]) * 0.0625;
        feats_out[(size_t)bn * 64 + tid] = s;
        double sh = (mask[bn] == 0) ? 999.0 : 0.0;
        double v = s + sh;
        double s2 = v * v, s1 = v;
        for (int off = 32; off > 0; off >>= 1) {
            s2 += __shfl_xor(s2, off, 64);
            s1 += __shfl_xor(s1, off, 64);
        }
        if (tid == 0) { rm[bn] = s2; Sq[bn] = s1; }
    }
}

// ---------------------------------------------------------------------------
// Block-2 kNN: F=64 f64 feats, top-17 drop-first.
// 4 queries per 256-thread block; LDS-staged 64-candidate tiles (padded,
// transposed); rm/Sq hoisted; distances in registers, barrier-free selection.
// ---------------------------------------------------------------------------
__global__ __launch_bounds__(256, 2) void knn2(const double* __restrict__ feats,
                                               const int* __restrict__ mask,
                                               const double* __restrict__ rm,
                                               const double* __restrict__ Sq,
                                               int* __restrict__ idx_out) {
    __shared__ double tileT[64][65];   // [f][c], pad -> 2-way alias (free)
    __shared__ double qsh[4][64];
    __shared__ double qrn[4], qSq[4];
    const int bid = ((blockIdx.x & 7) << 10) + (blockIdx.x >> 3);  // 8192/8 = 1024
    const int b = bid >> 7;
    const int n0 = (bid & 127) * 4;
    const int tid = threadIdx.x;
    const int w = tid >> 6, lane = tid & 63;
    const int n = n0 + w;

    {
        double sh = (mask[b * NN + n] == 0) ? 999.0 : 0.0;
        qsh[w][lane] = feats[(size_t)(b * NN + n) * 64 + lane] + sh;
        if (lane == 0) { qrn[w] = rm[b * NN + n]; qSq[w] = Sq[b * NN + n]; }
    }
    __syncthreads();

    double d[8];
    #pragma unroll
    for (int t = 0; t < 8; ++t) {
        #pragma unroll
        for (int i = 0; i < 16; ++i) {
            int e = tid + 256 * i;
            int f = e & 63, c = e >> 6;
            tileT[f][c] = feats[(size_t)(b * NN + t * 64 + c) * 64 + f];
        }
        __syncthreads();
        int m = t * 64 + lane;
        double sh_m = (mask[b * NN + m] == 0) ? 999.0 : 0.0;
        double a0 = 0.0, a1 = 0.0, a2 = 0.0, a3 = 0.0;
        for (int f = 0; f < 64; f += 4) {
            a0 += qsh[w][f + 0] * tileT[f + 0][lane];
            a1 += qsh[w][f + 1] * tileT[f + 1][lane];
            a2 += qsh[w][f + 2] * tileT[f + 2][lane];
            a3 += qsh[w][f + 3] * tileT[f + 3][lane];
        }
        double dot = (a0 + a1) + (a2 + a3);
        d[t] = qrn[w] + rm[b * NN + m] - 2.0 * (dot + sh_m * qSq[w]) + 1e-5;
        __syncthreads();
    }

    int* orow = idx_out + (size_t)(b * NN + n) * KK;
    SELECT_TOP17(d, lane, orow[it - 1] = bi)
}

// ---------------------------------------------------------------------------
// Block-2 MLP in f32 + mean + final mask. One 256-thread block per (b, n).
// Same register discipline as mlp1 (unroll 2 + (256,2) cap).
// ---------------------------------------------------------------------------
__global__ __launch_bounds__(256, 2) void mlp2_f32(const double* __restrict__ feats,
                                                   const int* __restrict__ idx,
                                                   const float* __restrict__ W1,
                                                   const float* __restrict__ b1,
                                                   const float* __restrict__ W2,
                                                   const float* __restrict__ b2,
                                                   const int* __restrict__ mask,
                                                   float* __restrict__ out) {
    const int C = 64;
    __shared__ float ctr[64];
    __shared__ float edg[KK][64];
    __shared__ float H1[KK][128];
    __shared__ float part[4][64];
    const int swz = ((blockIdx.x & 7) << 12) + (blockIdx.x >> 3);
    const int b = swz >> 9;
    const int bn = swz;
    const int tid = threadIdx.x;

    if (tid < C) ctr[tid] = (float)feats[(size_t)bn * C + tid];
    __syncthreads();
    for (int e = tid; e < KK * C; e += 256) {
        int k = e >> 6, c = e & 63;
        int m = idx[bn * KK + k];
        edg[k][c] = (float)feats[((size_t)b * NN + m) * C + c] - ctr[c];
    }
    __syncthreads();

    {   // layer 1
        const int j = tid & 127;
        const int kb = (tid >> 7) * 8;
        float cterm = b1[j];
        #pragma unroll 2
        for (int c = 0; c < C; ++c) cterm += ctr[c] * W1[(C + c) * 128 + j];
        float acc[8];
        #pragma unroll
        for (int kk = 0; kk < 8; ++kk) acc[kk] = cterm;
        #pragma unroll 2
        for (int c = 0; c < C; ++c) {
            float w = W1[c * 128 + j];
            #pragma unroll
            for (int kk = 0; kk < 8; ++kk) acc[kk] += edg[kb + kk][c] * w;
        }
        #pragma unroll
        for (int kk = 0; kk < 8; ++kk) H1[kb + kk][j] = gelu32(acc[kk]);
    }
    __syncthreads();

    {   // layer 2: each thread sums its own 4 GELU outputs
        const int j = tid & 63;
        const int g = tid >> 6;
        const int kb = g * 4;
        float acc[4];
        #pragma unroll
        for (int kk = 0; kk < 4; ++kk) acc[kk] = b2[j];
        #pragma unroll 2
        for (int c = 0; c < 128; ++c) {
            float w = W2[c * 64 + j];
            #pragma unroll
            for (int kk = 0; kk < 4; ++kk) acc[kk] += H1[kb + kk][c] * w;
        }
        float s = 0.0f;
        #pragma unroll
        for (int kk = 0; kk < 4; ++kk) s += gelu32(acc[kk]);
        part[g][j] = s;
    }
    __syncthreads();

    if (tid < 64) {
        float s = (part[0][tid] + part[1][tid] + part[2][tid] + part[3][tid]) * 0.0625f;
        if (mask[bn] == 0) s = 0.0f;
        out[(size_t)bn * 64 + tid] = s;
    }
}

extern "C" void kernel_launch(void* const* d_in, const int* in_sizes, int n_in,
                              void* d_out, int out_size, void* d_ws, size_t ws_size,
                              hipStream_t stream) {
    const float* x      = (const float*)d_in[0];
    const float* points = (const float*)d_in[1];
    const int*   mask   = (const int*)d_in[2];
    const float* W1_0 = (const float*)d_in[3];
    const float* b1_0 = (const float*)d_in[4];
    const float* W2_0 = (const float*)d_in[5];
    const float* b2_0 = (const float*)d_in[6];
    const float* W1_1 = (const float*)d_in[7];
    const float* b1_1 = (const float*)d_in[8];
    const float* W2_1 = (const float*)d_in[9];
    const float* b2_1 = (const float*)d_in[10];

    char* ws = (char*)d_ws;
    double2* tab    = (double2*)ws;                       //   16 KB (672*16 used)
    int*     idx    = (int*)(ws + 16384);                 //    2 MB
    double*  feats1 = (double*)(ws + 16384 + 2097152);    // 16.8 MB
    double*  rm     = (double*)(ws + 16384 + 2097152 + 16777216);           // 256 KB
    double*  Sq     = (double*)(ws + 16384 + 2097152 + 16777216 + 262144);  // 256 KB

    build_tab<<<1, 256, 0, stream>>>(tab);
    knn1<<<BB * NN / 4, 256, 0, stream>>>(points, mask, idx);
    mlp1_f64<<<BB * NN, 256, 0, stream>>>(x, idx, W1_0, b1_0, W2_0, b2_0, tab, mask, feats1, rm, Sq);
    knn2<<<BB * NN / 4, 256, 0, stream>>>(feats1, mask, rm, Sq, idx);
    mlp2_f32<<<BB * NN, 256, 0, stream>>>(feats1, idx, W1_1, b1_1, W2_1, b2_1, mask, (float*)d_out);
}

// Round 6
// 1418.769 us; speedup vs baseline: 5.1406x; 1.0775x over previous
//
#include <hip/hip_runtime.h>
#include <math.h>

#define BB 64
#define NN 512
#define KK 16

// ---------------------------------------------------------------------------
// GELU helpers
// ---------------------------------------------------------------------------
__device__ __forceinline__ float gelu32(float x) {
    return 0.5f * x * (1.0f + erff(x * 0.70710678118654752440f));
}

// Table-based f64 GELU: erf(z) via nearest-node cubic Taylor, h = 1/128.
// abs error <= ~5e-11; tail cutoff |x| >= 7.4 (erfc(5.23) ~ 1.4e-13).
#define TAB_N 672
__device__ __forceinline__ double gelu64_tab(double x, const double2* s_tab) {
    double ax = fabs(x);
    if (ax >= 7.4) return x > 0.0 ? x : 0.0;
    double z = ax * 0.70710678118654752440;
    double u = z * 128.0;
    int i = (int)(u + 0.5);
    double zi = (double)i * (1.0 / 128.0);
    double d = z - zi;
    double2 t = s_tab[i];
    // erf(zi + d) = E + G*(d - zi*d^2 + (2*zi^2-1)/3 * d^3)
    double poly = d * (1.0 + d * (-zi + d * ((2.0 * zi * zi - 1.0) * (1.0 / 3.0))));
    double er = t.x + t.y * poly;
    double s = (x > 0.0) ? er : -er;
    return 0.5 * x * (1.0 + s);
}

__global__ void build_tab(double2* __restrict__ g_tab) {
    for (int i = threadIdx.x; i < TAB_N; i += 256) {
        double z = (double)i * (1.0 / 128.0);
        double2 e;
        e.x = erf(z);
        e.y = 1.12837916709551257390 * exp(-z * z);  // 2/sqrt(pi) * exp(-z^2)
        g_tab[i] = e;
    }
}

// ---------------------------------------------------------------------------
// Wave-local top-17 extraction from 8 register-resident candidates per lane.
// No LDS, no barriers. Tie-break: lexicographic (dist, index), identical to
// jax.lax.top_k on negated distances. Winner-removal uses compile-time
// indices only (runtime-indexed reg arrays go to scratch — rule #20).
// ---------------------------------------------------------------------------
#define SELECT_TOP17(d, lane, OUT_STMT)                                        \
    for (int it = 0; it <= KK; ++it) {                                         \
        double bd = d[0];                                                      \
        int bi = lane;                                                         \
        _Pragma("unroll")                                                      \
        for (int i = 1; i < 8; ++i) {                                          \
            int m = lane + 64 * i;                                             \
            if (d[i] < bd) { bd = d[i]; bi = m; }                              \
        }                                                                      \
        for (int off = 32; off > 0; off >>= 1) {                               \
            double od = __shfl_xor(bd, off, 64);                               \
            int    oi = __shfl_xor(bi, off, 64);                               \
            if (od < bd || (od == bd && oi < bi)) { bd = od; bi = oi; }        \
        }                                                                      \
        const int wl = bi & 63, wsl = bi >> 6;                                 \
        _Pragma("unroll")                                                      \
        for (int i = 0; i < 8; ++i)                                            \
            if (lane == wl && i == wsl) d[i] = 1e300;                          \
        if (it > 0 && lane == 0) { OUT_STMT; }                                 \
    }

// ---------------------------------------------------------------------------
// Per-point layer-1 projections (linear decomposition of the edge MLP):
// U1[row][j] = sum_{c<32} x[row][c] * W1a[c][j]   (f64)
// ---------------------------------------------------------------------------
__global__ __launch_bounds__(256) void uv1(const float* __restrict__ x,
                                           const float* __restrict__ W1,
                                           double* __restrict__ U1) {
    __shared__ double xs[2][32];
    const int row0 = blockIdx.x * 2;
    const int tid = threadIdx.x;
    const int r = tid >> 7, j = tid & 127;
    if (tid < 64) xs[tid >> 5][tid & 31] = (double)x[(size_t)row0 * 32 + tid];
    __syncthreads();
    double acc = 0.0;
    #pragma unroll 4
    for (int c = 0; c < 32; ++c) acc += xs[r][c] * (double)W1[c * 128 + j];
    U1[(size_t)(row0 + r) * 128 + j] = acc;
}

// U2[row][j] = sum_{c<64} feats1[row][c] * W1a_1[c][j]   (f32)
__global__ __launch_bounds__(256) void uv2(const double* __restrict__ feats,
                                           const float* __restrict__ W1,
                                           float* __restrict__ U2) {
    __shared__ float fs[2][64];
    const int row0 = blockIdx.x * 2;
    const int tid = threadIdx.x;
    const int r = tid >> 7, j = tid & 127;
    if (tid < 128) fs[tid >> 6][tid & 63] = (float)feats[(size_t)row0 * 64 + tid];
    __syncthreads();
    float acc = 0.0f;
    #pragma unroll 4
    for (int c = 0; c < 64; ++c) acc += fs[r][c] * W1[c * 128 + j];
    U2[(size_t)(row0 + r) * 128 + j] = acc;
}

// ---------------------------------------------------------------------------
// Block-1 kNN: F=3 points (+999 mask shift), f64, top-17 drop-first.
// ---------------------------------------------------------------------------
__global__ __launch_bounds__(256, 4) void knn1(const float* __restrict__ points,
                                               const int* __restrict__ mask,
                                               int* __restrict__ idx_out) {
    __shared__ double pts[3][NN];    // transposed: 2-way bank alias (free)
    const int b = blockIdx.x >> 7;          // 128 blocks per batch
    const int n0 = (blockIdx.x & 127) * 4;
    const int tid = threadIdx.x;
    const int w = tid >> 6, lane = tid & 63;

    for (int e = tid; e < NN; e += 256) {
        double sh = (mask[b * NN + e] == 0) ? 999.0 : 0.0;
        const float* p = points + ((size_t)b * NN + e) * 3;
        pts[0][e] = (double)p[0] + sh;
        pts[1][e] = (double)p[1] + sh;
        pts[2][e] = (double)p[2] + sh;
    }
    __syncthreads();

    const int n = n0 + w;
    const double q0 = pts[0][n], q1 = pts[1][n], q2 = pts[2][n];
    double d[8];
    #pragma unroll
    for (int i = 0; i < 8; ++i) {
        int m = lane + 64 * i;
        double d0 = q0 - pts[0][m], d1 = q1 - pts[1][m], d2 = q2 - pts[2][m];
        d[i] = d0 * d0 + d1 * d1 + d2 * d2;   // +1e-5 const: ordering-invariant
    }

    int* orow = idx_out + (size_t)(b * NN + n) * KK;
    SELECT_TOP17(d, lane, orow[it - 1] = bi)
}

// ---------------------------------------------------------------------------
// Block-1 MLP in f64 (table GELU) + fused rm/Sq precompute for knn2.
// Layer 1 via UV decomposition when use_uv: in = U1[m][j] + Tn[j] where
// Tn[j] = b1[j] + sum_c ctr[c]*(W1b[c][j] - W1a[c][j]).
// Register discipline: `#pragma unroll 2` bounds the live-value window so the
// kernel fits the (256,2) 128-VGPR cap without spilling.
// ---------------------------------------------------------------------------
__global__ __launch_bounds__(256, 2) void mlp1_f64(const float* __restrict__ x,
                                                   const int* __restrict__ idx,
                                                   const float* __restrict__ W1,
                                                   const float* __restrict__ b1,
                                                   const float* __restrict__ W2,
                                                   const float* __restrict__ b2,
                                                   const double2* __restrict__ g_tab,
                                                   const int* __restrict__ mask,
                                                   const double* __restrict__ U1,
                                                   int use_uv,
                                                   double* __restrict__ feats_out,
                                                   double* __restrict__ rm,
                                                   double* __restrict__ Sq) {
    const int C = 32;
    __shared__ double2 s_tab[TAB_N];   // 10.5 KB
    __shared__ double ctr[32];
    __shared__ double edg[KK][32];     //  4 KB (fallback path only)
    __shared__ double H1[KK][128];     // 16 KB
    __shared__ double part[4][64];     //  2 KB
    const int swz = ((blockIdx.x & 7) << 12) + (blockIdx.x >> 3);  // 32768/8 = 4096
    const int b = swz >> 9;
    const int bn = swz;
    const int tid = threadIdx.x;

    for (int i = tid; i < TAB_N; i += 256) s_tab[i] = g_tab[i];
    if (tid < C) ctr[tid] = (double)x[(size_t)bn * C + tid];
    __syncthreads();

    if (use_uv) {
        // layer 1 via per-point projections
        const int j = tid & 127;
        const int kb = (tid >> 7) * 8;
        double tn = (double)b1[j];
        #pragma unroll 2
        for (int c = 0; c < C; ++c)
            tn += ctr[c] * ((double)W1[(C + c) * 128 + j] - (double)W1[c * 128 + j]);
        #pragma unroll
        for (int kk = 0; kk < 8; ++kk) {
            int m = idx[bn * KK + kb + kk];
            double v = U1[(size_t)(b * NN + m) * 128 + j] + tn;
            H1[kb + kk][j] = gelu64_tab(v, s_tab);
        }
    } else {
        // fallback: direct edge gather + per-edge layer 1
        for (int e = tid; e < KK * C; e += 256) {
            int k = e >> 5, c = e & 31;
            int m = idx[bn * KK + k];
            edg[k][c] = (double)x[((size_t)b * NN + m) * C + c] - ctr[c];
        }
        __syncthreads();
        const int j = tid & 127;
        const int kb = (tid >> 7) * 8;
        double cterm = (double)b1[j];
        #pragma unroll 2
        for (int c = 0; c < C; ++c) cterm += ctr[c] * (double)W1[(C + c) * 128 + j];
        double acc[8];
        #pragma unroll
        for (int kk = 0; kk < 8; ++kk) acc[kk] = cterm;
        #pragma unroll 2
        for (int c = 0; c < C; ++c) {
            double w = (double)W1[c * 128 + j];
            #pragma unroll
            for (int kk = 0; kk < 8; ++kk) acc[kk] += edg[kb + kk][c] * w;
        }
        #pragma unroll
        for (int kk = 0; kk < 8; ++kk) H1[kb + kk][j] = gelu64_tab(acc[kk], s_tab);
    }
    __syncthreads();

    {   // layer 2: thread -> (j = tid&63, k-group g = tid>>6 of 4);
        // each thread sums its own 4 GELU outputs -> part[g][j]
        const int j = tid & 63;
        const int g = tid >> 6;
        const int kb = g * 4;
        double acc[4];
        #pragma unroll
        for (int kk = 0; kk < 4; ++kk) acc[kk] = (double)b2[j];
        #pragma unroll 2
        for (int c = 0; c < 128; ++c) {
            double w = (double)W2[c * 64 + j];
            #pragma unroll
            for (int kk = 0; kk < 4; ++kk) acc[kk] += H1[kb + kk][c] * w;
        }
        double s = 0.0;
        #pragma unroll
        for (int kk = 0; kk < 4; ++kk) s += gelu64_tab(acc[kk], s_tab);
        part[g][j] = s;
    }
    __syncthreads();

    if (tid < 64) {   // wave 0 exactly: epilogue + fused rm/Sq reduction
        double s = (part[0][tid] + part[1][tid] + part[2][tid] + part[3][tid]) * 0.0625;
        feats_out[(size_t)bn * 64 + tid] = s;
        double sh = (mask[bn] == 0) ? 999.0 : 0.0;
        double v = s + sh;
        double s2 = v * v, s1 = v;
        for (int off = 32; off > 0; off >>= 1) {
            s2 += __shfl_xor(s2, off, 64);
            s1 += __shfl_xor(s1, off, 64);
        }
        if (tid == 0) { rm[bn] = s2; Sq[bn] = s1; }
    }
}

// ---------------------------------------------------------------------------
// Block-2 kNN: F=64 f64 feats, top-17 drop-first.
// ---------------------------------------------------------------------------
__global__ __launch_bounds__(256, 2) void knn2(const double* __restrict__ feats,
                                               const int* __restrict__ mask,
                                               const double* __restrict__ rm,
                                               const double* __restrict__ Sq,
                                               int* __restrict__ idx_out) {
    __shared__ double tileT[64][65];   // [f][c], pad -> 2-way alias (free)
    __shared__ double qsh[4][64];
    __shared__ double qrn[4], qSq[4];
    const int bid = ((blockIdx.x & 7) << 10) + (blockIdx.x >> 3);  // 8192/8 = 1024
    const int b = bid >> 7;
    const int n0 = (bid & 127) * 4;
    const int tid = threadIdx.x;
    const int w = tid >> 6, lane = tid & 63;
    const int n = n0 + w;

    {
        double sh = (mask[b * NN + n] == 0) ? 999.0 : 0.0;
        qsh[w][lane] = feats[(size_t)(b * NN + n) * 64 + lane] + sh;
        if (lane == 0) { qrn[w] = rm[b * NN + n]; qSq[w] = Sq[b * NN + n]; }
    }
    __syncthreads();

    double d[8];
    #pragma unroll
    for (int t = 0; t < 8; ++t) {
        #pragma unroll
        for (int i = 0; i < 16; ++i) {
            int e = tid + 256 * i;
            int f = e & 63, c = e >> 6;
            tileT[f][c] = feats[(size_t)(b * NN + t * 64 + c) * 64 + f];
        }
        __syncthreads();
        int m = t * 64 + lane;
        double sh_m = (mask[b * NN + m] == 0) ? 999.0 : 0.0;
        double a0 = 0.0, a1 = 0.0, a2 = 0.0, a3 = 0.0;
        for (int f = 0; f < 64; f += 4) {
            a0 += qsh[w][f + 0] * tileT[f + 0][lane];
            a1 += qsh[w][f + 1] * tileT[f + 1][lane];
            a2 += qsh[w][f + 2] * tileT[f + 2][lane];
            a3 += qsh[w][f + 3] * tileT[f + 3][lane];
        }
        double dot = (a0 + a1) + (a2 + a3);
        d[t] = qrn[w] + rm[b * NN + m] - 2.0 * (dot + sh_m * qSq[w]) + 1e-5;
        __syncthreads();
    }

    int* orow = idx_out + (size_t)(b * NN + n) * KK;
    SELECT_TOP17(d, lane, orow[it - 1] = bi)
}

// ---------------------------------------------------------------------------
// Block-2 MLP in f32 + mean + final mask. Layer 1 via UV when use_uv.
// ---------------------------------------------------------------------------
__global__ __launch_bounds__(256, 2) void mlp2_f32(const double* __restrict__ feats,
                                                   const int* __restrict__ idx,
                                                   const float* __restrict__ W1,
                                                   const float* __restrict__ b1,
                                                   const float* __restrict__ W2,
                                                   const float* __restrict__ b2,
                                                   const int* __restrict__ mask,
                                                   const float* __restrict__ U2,
                                                   int use_uv,
                                                   float* __restrict__ out) {
    const int C = 64;
    __shared__ float ctr[64];
    __shared__ float edg[KK][64];      // fallback path only
    __shared__ float H1[KK][128];
    __shared__ float part[4][64];
    const int swz = ((blockIdx.x & 7) << 12) + (blockIdx.x >> 3);
    const int b = swz >> 9;
    const int bn = swz;
    const int tid = threadIdx.x;

    if (tid < C) ctr[tid] = (float)feats[(size_t)bn * C + tid];
    __syncthreads();

    if (use_uv) {
        const int j = tid & 127;
        const int kb = (tid >> 7) * 8;
        float tn = b1[j];
        #pragma unroll 2
        for (int c = 0; c < C; ++c)
            tn += ctr[c] * (W1[(C + c) * 128 + j] - W1[c * 128 + j]);
        #pragma unroll
        for (int kk = 0; kk < 8; ++kk) {
            int m = idx[bn * KK + kb + kk];
            H1[kb + kk][j] = gelu32(U2[(size_t)(b * NN + m) * 128 + j] + tn);
        }
    } else {
        for (int e = tid; e < KK * C; e += 256) {
            int k = e >> 6, c = e & 63;
            int m = idx[bn * KK + k];
            edg[k][c] = (float)feats[((size_t)b * NN + m) * C + c] - ctr[c];
        }
        __syncthreads();
        const int j = tid & 127;
        const int kb = (tid >> 7) * 8;
        float cterm = b1[j];
        #pragma unroll 2
        for (int c = 0; c < C; ++c) cterm += ctr[c] * W1[(C + c) * 128 + j];
        float acc[8];
        #pragma unroll
        for (int kk = 0; kk < 8; ++kk) acc[kk] = cterm;
        #pragma unroll 2
        for (int c = 0; c < C; ++c) {
            float w = W1[c * 128 + j];
            #pragma unroll
            for (int kk = 0; kk < 8; ++kk) acc[kk] += edg[kb + kk][c] * w;
        }
        #pragma unroll
        for (int kk = 0; kk < 8; ++kk) H1[kb + kk][j] = gelu32(acc[kk]);
    }
    __syncthreads();

    {   // layer 2: each thread sums its own 4 GELU outputs
        const int j = tid & 63;
        const int g = tid >> 6;
        const int kb = g * 4;
        float acc[4];
        #pragma unroll
        for (int kk = 0; kk < 4; ++kk) acc[kk] = b2[j];
        #pragma unroll 2
        for (int c = 0; c < 128; ++c) {
            float w = W2[c * 64 + j];
            #pragma unroll
            for (int kk = 0; kk < 4; ++kk) acc[kk] += H1[kb + kk][c] * w;
        }
        float s = 0.0f;
        #pragma unroll
        for (int kk = 0; kk < 4; ++kk) s += gelu32(acc[kk]);
        part[g][j] = s;
    }
    __syncthreads();

    if (tid < 64) {
        float s = (part[0][tid] + part[1][tid] + part[2][tid] + part[3][tid]) * 0.0625f;
        if (mask[bn] == 0) s = 0.0f;
        out[(size_t)bn * 64 + tid] = s;
    }
}

extern "C" void kernel_launch(void* const* d_in, const int* in_sizes, int n_in,
                              void* d_out, int out_size, void* d_ws, size_t ws_size,
                              hipStream_t stream) {
    const float* x      = (const float*)d_in[0];
    const float* points = (const float*)d_in[1];
    const int*   mask   = (const int*)d_in[2];
    const float* W1_0 = (const float*)d_in[3];
    const float* b1_0 = (const float*)d_in[4];
    const float* W2_0 = (const float*)d_in[5];
    const float* b2_0 = (const float*)d_in[6];
    const float* W1_1 = (const float*)d_in[7];
    const float* b1_1 = (const float*)d_in[8];
    const float* W2_1 = (const float*)d_in[9];
    const float* b2_1 = (const float*)d_in[10];

    char* ws = (char*)d_ws;
    const size_t off_tab   = 0;                      //   16 KB
    const size_t off_idx   = 16384;                  //    2 MB
    const size_t off_feats = off_idx + 2097152;      // 16.8 MB
    const size_t off_rm    = off_feats + 16777216;   //  256 KB
    const size_t off_sq    = off_rm + 262144;        //  256 KB
    const size_t off_u1    = off_sq + 262144;        // 33.5 MB
    const size_t off_u2    = off_u1 + 33554432;      // 16.8 MB
    const size_t need      = off_u2 + 16777216;      // ~69.8 MB total

    double2* tab    = (double2*)(ws + off_tab);
    int*     idx    = (int*)(ws + off_idx);
    double*  feats1 = (double*)(ws + off_feats);
    double*  rm     = (double*)(ws + off_rm);
    double*  Sq     = (double*)(ws + off_sq);
    double*  U1     = (double*)(ws + off_u1);
    float*   U2     = (float*)(ws + off_u2);

    const int use_uv = (ws_size >= need) ? 1 : 0;

    build_tab<<<1, 256, 0, stream>>>(tab);
    knn1<<<BB * NN / 4, 256, 0, stream>>>(points, mask, idx);
    if (use_uv) uv1<<<BB * NN / 2, 256, 0, stream>>>(x, W1_0, U1);
    mlp1_f64<<<BB * NN, 256, 0, stream>>>(x, idx, W1_0, b1_0, W2_0, b2_0, tab, mask,
                                          U1, use_uv, feats1, rm, Sq);
    if (use_uv) uv2<<<BB * NN / 2, 256, 0, stream>>>(feats1, W1_1, U2);
    knn2<<<BB * NN / 4, 256, 0, stream>>>(feats1, mask, rm, Sq, idx);
    mlp2_f32<<<BB * NN, 256, 0, stream>>>(feats1, idx, W1_1, b1_1, W2_1, b2_1, mask,
                                          U2, use_uv, (float*)d_out);
}

// Round 7
// 1289.684 us; speedup vs baseline: 5.6551x; 1.1001x over previous
//
#include <hip/hip_runtime.h>
#include <math.h>

#define BB 64
#define NN 512
#define KK 16

// ---------------------------------------------------------------------------
// GELU helpers
// ---------------------------------------------------------------------------
__device__ __forceinline__ float gelu32(float x) {
    return 0.5f * x * (1.0f + erff(x * 0.70710678118654752440f));
}

// Table-based f64 GELU: erf(z) via nearest-node cubic Taylor, h = 1/128.
// Table covers z <= 4.07 (|x| < 5.74); abs err <= ~5e-11 in range, ~3e-8 at
// the tail cutoff (gelu(|x|>=5.74) ~ relu to 3e-8) — invisible at the bf16
// comparison and far below knn2 rank-gap scale.
#define TAB_N 521
__device__ __forceinline__ double gelu64_tab(double x, const double2* s_tab) {
    double ax = fabs(x);
    if (ax >= 5.74) return x > 0.0 ? x : 0.0;
    double z = ax * 0.70710678118654752440;
    double u = z * 128.0;
    int i = (int)(u + 0.5);
    double zi = (double)i * (1.0 / 128.0);
    double d = z - zi;
    double2 t = s_tab[i];
    // erf(zi + d) = E + G*(d - zi*d^2 + (2*zi^2-1)/3 * d^3)
    double poly = d * (1.0 + d * (-zi + d * ((2.0 * zi * zi - 1.0) * (1.0 / 3.0))));
    double er = t.x + t.y * poly;
    double s = (x > 0.0) ? er : -er;
    return 0.5 * x * (1.0 + s);
}

__global__ void build_tab(double2* __restrict__ g_tab) {
    for (int i = threadIdx.x; i < TAB_N; i += 256) {
        double z = (double)i * (1.0 / 128.0);
        double2 e;
        e.x = erf(z);
        e.y = 1.12837916709551257390 * exp(-z * z);  // 2/sqrt(pi) * exp(-z^2)
        g_tab[i] = e;
    }
}

// ---------------------------------------------------------------------------
// Wave-local top-17 extraction from 8 register-resident candidates per lane.
// No LDS, no barriers. Tie-break: lexicographic (dist, index), identical to
// jax.lax.top_k on negated distances. Winner-removal uses compile-time
// indices only (runtime-indexed reg arrays go to scratch — rule #20).
// ---------------------------------------------------------------------------
#define SELECT_TOP17(d, lane, OUT_STMT)                                        \
    for (int it = 0; it <= KK; ++it) {                                         \
        double bd = d[0];                                                      \
        int bi = lane;                                                         \
        _Pragma("unroll")                                                      \
        for (int i = 1; i < 8; ++i) {                                          \
            int m = lane + 64 * i;                                             \
            if (d[i] < bd) { bd = d[i]; bi = m; }                              \
        }                                                                      \
        for (int off = 32; off > 0; off >>= 1) {                               \
            double od = __shfl_xor(bd, off, 64);                               \
            int    oi = __shfl_xor(bi, off, 64);                               \
            if (od < bd || (od == bd && oi < bi)) { bd = od; bi = oi; }        \
        }                                                                      \
        const int wl = bi & 63, wsl = bi >> 6;                                 \
        _Pragma("unroll")                                                      \
        for (int i = 0; i < 8; ++i)                                            \
            if (lane == wl && i == wsl) d[i] = 1e300;                          \
        if (it > 0 && lane == 0) { OUT_STMT; }                                 \
    }

// ---------------------------------------------------------------------------
// Per-point layer-1 projections (linear decomposition of the edge MLP):
// U1[row][j] = sum_{c<32} x[row][c] * W1a[c][j]   (f64)
// ---------------------------------------------------------------------------
__global__ __launch_bounds__(256) void uv1(const float* __restrict__ x,
                                           const float* __restrict__ W1,
                                           double* __restrict__ U1) {
    __shared__ double xs[2][32];
    const int row0 = blockIdx.x * 2;
    const int tid = threadIdx.x;
    const int r = tid >> 7, j = tid & 127;
    if (tid < 64) xs[tid >> 5][tid & 31] = (double)x[(size_t)row0 * 32 + tid];
    __syncthreads();
    double acc = 0.0;
    #pragma unroll 4
    for (int c = 0; c < 32; ++c) acc += xs[r][c] * (double)W1[c * 128 + j];
    U1[(size_t)(row0 + r) * 128 + j] = acc;
}

// U2[row][j] = sum_{c<64} feats1[row][c] * W1a_1[c][j]   (f32)
__global__ __launch_bounds__(256) void uv2(const double* __restrict__ feats,
                                           const float* __restrict__ W1,
                                           float* __restrict__ U2) {
    __shared__ float fs[2][64];
    const int row0 = blockIdx.x * 2;
    const int tid = threadIdx.x;
    const int r = tid >> 7, j = tid & 127;
    if (tid < 128) fs[tid >> 6][tid & 63] = (float)feats[(size_t)row0 * 64 + tid];
    __syncthreads();
    float acc = 0.0f;
    #pragma unroll 4
    for (int c = 0; c < 64; ++c) acc += fs[r][c] * W1[c * 128 + j];
    U2[(size_t)(row0 + r) * 128 + j] = acc;
}

// ---------------------------------------------------------------------------
// Block-1 kNN: F=3 points (+999 mask shift), f64, top-17 drop-first.
// 8 queries per 512-thread block (one wave per query); staging amortized 2x
// vs the 4-query version.
// ---------------------------------------------------------------------------
__global__ __launch_bounds__(512) void knn1(const float* __restrict__ points,
                                            const int* __restrict__ mask,
                                            int* __restrict__ idx_out) {
    __shared__ double pts[3][NN];    // 12 KB
    const int b = blockIdx.x >> 6;          // 64 blocks per batch
    const int n0 = (blockIdx.x & 63) * 8;
    const int tid = threadIdx.x;
    const int w = tid >> 6, lane = tid & 63;

    for (int e = tid; e < NN; e += 512) {
        double sh = (mask[b * NN + e] == 0) ? 999.0 : 0.0;
        const float* p = points + ((size_t)b * NN + e) * 3;
        pts[0][e] = (double)p[0] + sh;
        pts[1][e] = (double)p[1] + sh;
        pts[2][e] = (double)p[2] + sh;
    }
    __syncthreads();

    const int n = n0 + w;
    const double q0 = pts[0][n], q1 = pts[1][n], q2 = pts[2][n];
    double d[8];
    #pragma unroll
    for (int i = 0; i < 8; ++i) {
        int m = lane + 64 * i;
        double d0 = q0 - pts[0][m], d1 = q1 - pts[1][m], d2 = q2 - pts[2][m];
        d[i] = d0 * d0 + d1 * d1 + d2 * d2;   // +1e-5 const: ordering-invariant
    }

    int* orow = idx_out + (size_t)(b * NN + n) * KK;
    SELECT_TOP17(d, lane, orow[it - 1] = bi)
}

// ---------------------------------------------------------------------------
// Block-1 MLP in f64 (table GELU) + fused rm/Sq precompute for knn2.
// UV=1: layer 1 via per-point projections (in = U1[m][j] + Tn[j]).
// UV=0: fallback direct edge path (only launched if ws too small).
// Register discipline: `#pragma unroll 2` bounds the live-value window so the
// kernel fits the (256,2) 128-VGPR cap without spilling.
// LDS (UV=1): 8.3K tab + 16K H1 + 2K part + ctr ~= 27.0 KB -> 6 blocks/CU.
// ---------------------------------------------------------------------------
template<int UV>
__global__ __launch_bounds__(256, 2) void mlp1_f64(const float* __restrict__ x,
                                                   const int* __restrict__ idx,
                                                   const float* __restrict__ W1,
                                                   const float* __restrict__ b1,
                                                   const float* __restrict__ W2,
                                                   const float* __restrict__ b2,
                                                   const double2* __restrict__ g_tab,
                                                   const int* __restrict__ mask,
                                                   const double* __restrict__ U1,
                                                   double* __restrict__ feats_out,
                                                   double* __restrict__ rm,
                                                   double* __restrict__ Sq) {
    const int C = 32;
    __shared__ double2 s_tab[TAB_N];   // 8.3 KB
    __shared__ double ctr[32];
    __shared__ double H1[KK][128];     // 16 KB
    __shared__ double part[4][64];     //  2 KB
    const int swz = ((blockIdx.x & 7) << 12) + (blockIdx.x >> 3);  // 32768/8 = 4096
    const int b = swz >> 9;
    const int bn = swz;
    const int tid = threadIdx.x;

    for (int i = tid; i < TAB_N; i += 256) s_tab[i] = g_tab[i];
    if (tid < C) ctr[tid] = (double)x[(size_t)bn * C + tid];
    __syncthreads();

    if constexpr (UV) {
        // layer 1 via per-point projections
        const int j = tid & 127;
        const int kb = (tid >> 7) * 8;
        double tn = (double)b1[j];
        #pragma unroll 2
        for (int c = 0; c < C; ++c)
            tn += ctr[c] * ((double)W1[(C + c) * 128 + j] - (double)W1[c * 128 + j]);
        #pragma unroll
        for (int kk = 0; kk < 8; ++kk) {
            int m = idx[bn * KK + kb + kk];
            double v = U1[(size_t)(b * NN + m) * 128 + j] + tn;
            H1[kb + kk][j] = gelu64_tab(v, s_tab);
        }
    } else {
        __shared__ double edg[KK][32];
        for (int e = tid; e < KK * C; e += 256) {
            int k = e >> 5, c = e & 31;
            int m = idx[bn * KK + k];
            edg[k][c] = (double)x[((size_t)b * NN + m) * C + c] - ctr[c];
        }
        __syncthreads();
        const int j = tid & 127;
        const int kb = (tid >> 7) * 8;
        double cterm = (double)b1[j];
        #pragma unroll 2
        for (int c = 0; c < C; ++c) cterm += ctr[c] * (double)W1[(C + c) * 128 + j];
        double acc[8];
        #pragma unroll
        for (int kk = 0; kk < 8; ++kk) acc[kk] = cterm;
        #pragma unroll 2
        for (int c = 0; c < C; ++c) {
            double w = (double)W1[c * 128 + j];
            #pragma unroll
            for (int kk = 0; kk < 8; ++kk) acc[kk] += edg[kb + kk][c] * w;
        }
        #pragma unroll
        for (int kk = 0; kk < 8; ++kk) H1[kb + kk][j] = gelu64_tab(acc[kk], s_tab);
    }
    __syncthreads();

    {   // layer 2: thread -> (j = tid&63, k-group g = tid>>6 of 4);
        // each thread sums its own 4 GELU outputs -> part[g][j]
        const int j = tid & 63;
        const int g = tid >> 6;
        const int kb = g * 4;
        double acc[4];
        #pragma unroll
        for (int kk = 0; kk < 4; ++kk) acc[kk] = (double)b2[j];
        #pragma unroll 2
        for (int c = 0; c < 128; ++c) {
            double w = (double)W2[c * 64 + j];
            #pragma unroll
            for (int kk = 0; kk < 4; ++kk) acc[kk] += H1[kb + kk][c] * w;
        }
        double s = 0.0;
        #pragma unroll
        for (int kk = 0; kk < 4; ++kk) s += gelu64_tab(acc[kk], s_tab);
        part[g][j] = s;
    }
    __syncthreads();

    if (tid < 64) {   // wave 0 exactly: epilogue + fused rm/Sq reduction
        double s = (part[0][tid] + part[1][tid] + part[2][tid] + part[3][tid]) * 0.0625;
        feats_out[(size_t)bn * 64 + tid] = s;
        double sh = (mask[bn] == 0) ? 999.0 : 0.0;
        double v = s + sh;
        double s2 = v * v, s1 = v;
        for (int off = 32; off > 0; off >>= 1) {
            s2 += __shfl_xor(s2, off, 64);
            s1 += __shfl_xor(s1, off, 64);
        }
        if (tid == 0) { rm[bn] = s2; Sq[bn] = s1; }
    }
}

// ---------------------------------------------------------------------------
// Block-2 kNN: F=64 f64 feats, top-17 drop-first.
// 8 queries per 512-thread block; LDS-staged 64-candidate tiles shared by all
// 8 queries (staging amortized 2x); rm/Sq hoisted; register-resident select.
// LDS ~37.5 KB -> 4 blocks/CU x 8 waves = full occupancy.
// ---------------------------------------------------------------------------
__global__ __launch_bounds__(512) void knn2(const double* __restrict__ feats,
                                            const int* __restrict__ mask,
                                            const double* __restrict__ rm,
                                            const double* __restrict__ Sq,
                                            int* __restrict__ idx_out) {
    __shared__ double tileT[64][65];   // [f][c], 33.3 KB
    __shared__ double qsh[8][64];      // 4 KB
    __shared__ double qrn[8], qSq[8];
    const int bid = ((blockIdx.x & 7) << 9) + (blockIdx.x >> 3);  // 4096/8 = 512
    const int b = bid >> 6;
    const int n0 = (bid & 63) * 8;
    const int tid = threadIdx.x;
    const int w = tid >> 6, lane = tid & 63;
    const int n = n0 + w;

    {
        double sh = (mask[b * NN + n] == 0) ? 999.0 : 0.0;
        qsh[w][lane] = feats[(size_t)(b * NN + n) * 64 + lane] + sh;
        if (lane == 0) { qrn[w] = rm[b * NN + n]; qSq[w] = Sq[b * NN + n]; }
    }
    __syncthreads();

    double d[8];
    #pragma unroll
    for (int t = 0; t < 8; ++t) {
        #pragma unroll
        for (int i = 0; i < 8; ++i) {
            int e = tid + 512 * i;
            int f = e & 63, c = e >> 6;
            tileT[f][c] = feats[(size_t)(b * NN + t * 64 + c) * 64 + f];
        }
        __syncthreads();
        int m = t * 64 + lane;
        double sh_m = (mask[b * NN + m] == 0) ? 999.0 : 0.0;
        double a0 = 0.0, a1 = 0.0, a2 = 0.0, a3 = 0.0;
        for (int f = 0; f < 64; f += 4) {
            a0 += qsh[w][f + 0] * tileT[f + 0][lane];
            a1 += qsh[w][f + 1] * tileT[f + 1][lane];
            a2 += qsh[w][f + 2] * tileT[f + 2][lane];
            a3 += qsh[w][f + 3] * tileT[f + 3][lane];
        }
        double dot = (a0 + a1) + (a2 + a3);
        d[t] = qrn[w] + rm[b * NN + m] - 2.0 * (dot + sh_m * qSq[w]) + 1e-5;
        __syncthreads();
    }

    int* orow = idx_out + (size_t)(b * NN + n) * KK;
    SELECT_TOP17(d, lane, orow[it - 1] = bi)
}

// ---------------------------------------------------------------------------
// Block-2 MLP in f32 + mean + final mask. UV=1: layer 1 via projections.
// LDS (UV=1) ~9.3 KB -> wave-limited full occupancy.
// ---------------------------------------------------------------------------
template<int UV>
__global__ __launch_bounds__(256, 2) void mlp2_f32(const double* __restrict__ feats,
                                                   const int* __restrict__ idx,
                                                   const float* __restrict__ W1,
                                                   const float* __restrict__ b1,
                                                   const float* __restrict__ W2,
                                                   const float* __restrict__ b2,
                                                   const int* __restrict__ mask,
                                                   const float* __restrict__ U2,
                                                   float* __restrict__ out) {
    const int C = 64;
    __shared__ float ctr[64];
    __shared__ float H1[KK][128];
    __shared__ float part[4][64];
    const int swz = ((blockIdx.x & 7) << 12) + (blockIdx.x >> 3);
    const int b = swz >> 9;
    const int bn = swz;
    const int tid = threadIdx.x;

    if (tid < C) ctr[tid] = (float)feats[(size_t)bn * C + tid];
    __syncthreads();

    if constexpr (UV) {
        const int j = tid & 127;
        const int kb = (tid >> 7) * 8;
        float tn = b1[j];
        #pragma unroll 2
        for (int c = 0; c < C; ++c)
            tn += ctr[c] * (W1[(C + c) * 128 + j] - W1[c * 128 + j]);
        #pragma unroll
        for (int kk = 0; kk < 8; ++kk) {
            int m = idx[bn * KK + kb + kk];
            H1[kb + kk][j] = gelu32(U2[(size_t)(b * NN + m) * 128 + j] + tn);
        }
    } else {
        __shared__ float edg[KK][64];
        for (int e = tid; e < KK * C; e += 256) {
            int k = e >> 6, c = e & 63;
            int m = idx[bn * KK + k];
            edg[k][c] = (float)feats[((size_t)b * NN + m) * C + c] - ctr[c];
        }
        __syncthreads();
        const int j = tid & 127;
        const int kb = (tid >> 7) * 8;
        float cterm = b1[j];
        #pragma unroll 2
        for (int c = 0; c < C; ++c) cterm += ctr[c] * W1[(C + c) * 128 + j];
        float acc[8];
        #pragma unroll
        for (int kk = 0; kk < 8; ++kk) acc[kk] = cterm;
        #pragma unroll 2
        for (int c = 0; c < C; ++c) {
            float w = W1[c * 128 + j];
            #pragma unroll
            for (int kk = 0; kk < 8; ++kk) acc[kk] += edg[kb + kk][c] * w;
        }
        #pragma unroll
        for (int kk = 0; kk < 8; ++kk) H1[kb + kk][j] = gelu32(acc[kk]);
    }
    __syncthreads();

    {   // layer 2: each thread sums its own 4 GELU outputs
        const int j = tid & 63;
        const int g = tid >> 6;
        const int kb = g * 4;
        float acc[4];
        #pragma unroll
        for (int kk = 0; kk < 4; ++kk) acc[kk] = b2[j];
        #pragma unroll 2
        for (int c = 0; c < 128; ++c) {
            float w = W2[c * 64 + j];
            #pragma unroll
            for (int kk = 0; kk < 4; ++kk) acc[kk] += H1[kb + kk][c] * w;
        }
        float s = 0.0f;
        #pragma unroll
        for (int kk = 0; kk < 4; ++kk) s += gelu32(acc[kk]);
        part[g][j] = s;
    }
    __syncthreads();

    if (tid < 64) {
        float s = (part[0][tid] + part[1][tid] + part[2][tid] + part[3][tid]) * 0.0625f;
        if (mask[bn] == 0) s = 0.0f;
        out[(size_t)bn * 64 + tid] = s;
    }
}

extern "C" void kernel_launch(void* const* d_in, const int* in_sizes, int n_in,
                              void* d_out, int out_size, void* d_ws, size_t ws_size,
                              hipStream_t stream) {
    const float* x      = (const float*)d_in[0];
    const float* points = (const float*)d_in[1];
    const int*   mask   = (const int*)d_in[2];
    const float* W1_0 = (const float*)d_in[3];
    const float* b1_0 = (const float*)d_in[4];
    const float* W2_0 = (const float*)d_in[5];
    const float* b2_0 = (const float*)d_in[6];
    const float* W1_1 = (const float*)d_in[7];
    const float* b1_1 = (const float*)d_in[8];
    const float* W2_1 = (const float*)d_in[9];
    const float* b2_1 = (const float*)d_in[10];

    char* ws = (char*)d_ws;
    const size_t off_tab   = 0;                      //   16 KB reserved
    const size_t off_idx   = 16384;                  //    2 MB
    const size_t off_feats = off_idx + 2097152;      // 16.8 MB
    const size_t off_rm    = off_feats + 16777216;   //  256 KB
    const size_t off_sq    = off_rm + 262144;        //  256 KB
    const size_t off_u1    = off_sq + 262144;        // 33.5 MB
    const size_t off_u2    = off_u1 + 33554432;      // 16.8 MB
    const size_t need      = off_u2 + 16777216;      // ~69.8 MB total

    double2* tab    = (double2*)(ws + off_tab);
    int*     idx    = (int*)(ws + off_idx);
    double*  feats1 = (double*)(ws + off_feats);
    double*  rm     = (double*)(ws + off_rm);
    double*  Sq     = (double*)(ws + off_sq);
    double*  U1     = (double*)(ws + off_u1);
    float*   U2     = (float*)(ws + off_u2);

    const int use_uv = (ws_size >= need) ? 1 : 0;

    build_tab<<<1, 256, 0, stream>>>(tab);
    knn1<<<BB * NN / 8, 512, 0, stream>>>(points, mask, idx);
    if (use_uv) {
        uv1<<<BB * NN / 2, 256, 0, stream>>>(x, W1_0, U1);
        mlp1_f64<1><<<BB * NN, 256, 0, stream>>>(x, idx, W1_0, b1_0, W2_0, b2_0, tab,
                                                 mask, U1, feats1, rm, Sq);
        uv2<<<BB * NN / 2, 256, 0, stream>>>(feats1, W1_1, U2);
        knn2<<<BB * NN / 8, 512, 0, stream>>>(feats1, mask, rm, Sq, idx);
        mlp2_f32<1><<<BB * NN, 256, 0, stream>>>(feats1, idx, W1_1, b1_1, W2_1, b2_1,
                                                 mask, U2, (float*)d_out);
    } else {
        mlp1_f64<0><<<BB * NN, 256, 0, stream>>>(x, idx, W1_0, b1_0, W2_0, b2_0, tab,
                                                 mask, U1, feats1, rm, Sq);
        knn2<<<BB * NN / 8, 512, 0, stream>>>(feats1, mask, rm, Sq, idx);
        mlp2_f32<0><<<BB * NN, 256, 0, stream>>>(feats1, idx, W1_1, b1_1, W2_1, b2_1,
                                                 mask, U2, (float*)d_out);
    }
}

// Round 8
// 802.305 us; speedup vs baseline: 9.0904x; 1.6075x over previous
//
#include <hip/hip_runtime.h>
#include <math.h>

#define BB 64
#define NN 512
#define KK 16

// ---------------------------------------------------------------------------
// GELU helpers
// ---------------------------------------------------------------------------
__device__ __forceinline__ float gelu32(float x) {
    return 0.5f * x * (1.0f + erff(x * 0.70710678118654752440f));
}

// Table-based f64 GELU: erf(z) via nearest-node cubic Taylor, h = 1/128.
// Table covers z <= 4.07 (|x| < 5.74); abs err <= ~5e-11 in range, ~3e-8 at
// the tail cutoff — invisible at the bf16 comparison and far below knn2
// rank-gap scale.
#define TAB_N 521
__device__ __forceinline__ double gelu64_tab(double x, const double2* s_tab) {
    double ax = fabs(x);
    if (ax >= 5.74) return x > 0.0 ? x : 0.0;
    double z = ax * 0.70710678118654752440;
    double u = z * 128.0;
    int i = (int)(u + 0.5);
    double zi = (double)i * (1.0 / 128.0);
    double d = z - zi;
    double2 t = s_tab[i];
    // erf(zi + d) = E + G*(d - zi*d^2 + (2*zi^2-1)/3 * d^3)
    double poly = d * (1.0 + d * (-zi + d * ((2.0 * zi * zi - 1.0) * (1.0 / 3.0))));
    double er = t.x + t.y * poly;
    double s = (x > 0.0) ? er : -er;
    return 0.5 * x * (1.0 + s);
}

__global__ void build_tab(double2* __restrict__ g_tab) {
    for (int i = threadIdx.x; i < TAB_N; i += 256) {
        double z = (double)i * (1.0 / 128.0);
        double2 e;
        e.x = erf(z);
        e.y = 1.12837916709551257390 * exp(-z * z);  // 2/sqrt(pi) * exp(-z^2)
        g_tab[i] = e;
    }
}

// ---------------------------------------------------------------------------
// Wave-local top-17 extraction from 8 register-resident candidates per lane.
// No LDS, no barriers. Tie-break: lexicographic (dist, index), identical to
// jax.lax.top_k on negated distances. Winner-removal uses compile-time
// indices only (runtime-indexed reg arrays go to scratch — rule #20).
// ---------------------------------------------------------------------------
#define SELECT_TOP17(d, lane, OUT_STMT)                                        \
    for (int it = 0; it <= KK; ++it) {                                         \
        double bd = d[0];                                                      \
        int bi = lane;                                                         \
        _Pragma("unroll")                                                      \
        for (int i = 1; i < 8; ++i) {                                          \
            int m = lane + 64 * i;                                             \
            if (d[i] < bd) { bd = d[i]; bi = m; }                              \
        }                                                                      \
        for (int off = 32; off > 0; off >>= 1) {                               \
            double od = __shfl_xor(bd, off, 64);                               \
            int    oi = __shfl_xor(bi, off, 64);                               \
            if (od < bd || (od == bd && oi < bi)) { bd = od; bi = oi; }        \
        }                                                                      \
        const int wl = bi & 63, wsl = bi >> 6;                                 \
        _Pragma("unroll")                                                      \
        for (int i = 0; i < 8; ++i)                                            \
            if (lane == wl && i == wsl) d[i] = 1e300;                          \
        if (it > 0 && lane == 0) { OUT_STMT; }                                 \
    }

// ---------------------------------------------------------------------------
// Per-point layer-1 projections (linear decomposition of the edge MLP):
// U1[row][j] = sum_{c<32} x[row][c] * W1a[c][j]   (f64)
// Masked rows skipped: their U is only ever gathered by masked queries'
// (irrelevant) MLPs.
// ---------------------------------------------------------------------------
__global__ __launch_bounds__(256) void uv1(const float* __restrict__ x,
                                           const float* __restrict__ W1,
                                           const int* __restrict__ mask,
                                           double* __restrict__ U1) {
    __shared__ double xs[2][32];
    const int row0 = blockIdx.x * 2;
    const int tid = threadIdx.x;
    const int r = tid >> 7, j = tid & 127;
    if (tid < 64) xs[tid >> 5][tid & 31] = (double)x[(size_t)row0 * 32 + tid];
    __syncthreads();
    if (mask[row0 + r] == 0) return;   // wave-uniform (r fixed per wave)
    double acc = 0.0;
    #pragma unroll 4
    for (int c = 0; c < 32; ++c) acc += xs[r][c] * (double)W1[c * 128 + j];
    U1[(size_t)(row0 + r) * 128 + j] = acc;
}

// U2[row][j] = sum_{c<64} feats1[row][c] * W1a_1[c][j]   (f32)
__global__ __launch_bounds__(256) void uv2(const double* __restrict__ feats,
                                           const float* __restrict__ W1,
                                           const int* __restrict__ mask,
                                           float* __restrict__ U2) {
    __shared__ float fs[2][64];
    const int row0 = blockIdx.x * 2;
    const int tid = threadIdx.x;
    const int r = tid >> 7, j = tid & 127;
    if (tid < 128) fs[tid >> 6][tid & 63] = (float)feats[(size_t)row0 * 64 + tid];
    __syncthreads();
    if (mask[row0 + r] == 0) return;
    float acc = 0.0f;
    #pragma unroll 4
    for (int c = 0; c < 64; ++c) acc += fs[r][c] * W1[c * 128 + j];
    U2[(size_t)(row0 + r) * 128 + j] = acc;
}

// ---------------------------------------------------------------------------
// Block-1 kNN: F=3 points (+999 mask shift), f64, top-17 drop-first.
// 8 queries per 512-thread block. Masked queries: nothing downstream reads
// their idx (mlp1 skips masked rows) -> wave exits after staging.
// ---------------------------------------------------------------------------
__global__ __launch_bounds__(512) void knn1(const float* __restrict__ points,
                                            const int* __restrict__ mask,
                                            int* __restrict__ idx_out) {
    __shared__ double pts[3][NN];    // 12 KB
    const int b = blockIdx.x >> 6;          // 64 blocks per batch
    const int n0 = (blockIdx.x & 63) * 8;
    const int tid = threadIdx.x;
    const int w = tid >> 6, lane = tid & 63;

    for (int e = tid; e < NN; e += 512) {
        double sh = (mask[b * NN + e] == 0) ? 999.0 : 0.0;
        const float* p = points + ((size_t)b * NN + e) * 3;
        pts[0][e] = (double)p[0] + sh;
        pts[1][e] = (double)p[1] + sh;
        pts[2][e] = (double)p[2] + sh;
    }
    __syncthreads();

    const int n = n0 + w;
    if (mask[b * NN + n] == 0) return;   // wave-uniform; no barriers below
    const double q0 = pts[0][n], q1 = pts[1][n], q2 = pts[2][n];
    double d[8];
    #pragma unroll
    for (int i = 0; i < 8; ++i) {
        int m = lane + 64 * i;
        double d0 = q0 - pts[0][m], d1 = q1 - pts[1][m], d2 = q2 - pts[2][m];
        d[i] = d0 * d0 + d1 * d1 + d2 * d2;   // +1e-5 const: ordering-invariant
    }

    int* orow = idx_out + (size_t)(b * NN + n) * KK;
    SELECT_TOP17(d, lane, orow[it - 1] = bi)
}

// ---------------------------------------------------------------------------
// Block-1 MLP in f64 (table GELU) + fused rm/Sq precompute for knn2.
// Masked rows: skipped entirely; rm sentinel 1e18 guarantees masked
// candidates lose every unmasked query's top-17 (true distances ~6.4e7 vs
// unmasked ~1e3; sentinel preserves the "masked always lose" ordering with
// 1e15x margin over the |2*999*qSq| <= ~3e5 term). feats1[masked] stays
// stale-poison (~ -3e-103, NaN-free) and only enters those lost candidates.
// UV=1: layer 1 via per-point projections (in = U1[m][j] + Tn[j]).
// Register discipline: `#pragma unroll 2` bounds the live-value window so the
// kernel fits the (256,2) 128-VGPR cap without spilling.
// ---------------------------------------------------------------------------
template<int UV>
__global__ __launch_bounds__(256, 2) void mlp1_f64(const float* __restrict__ x,
                                                   const int* __restrict__ idx,
                                                   const float* __restrict__ W1,
                                                   const float* __restrict__ b1,
                                                   const float* __restrict__ W2,
                                                   const float* __restrict__ b2,
                                                   const double2* __restrict__ g_tab,
                                                   const int* __restrict__ mask,
                                                   const double* __restrict__ U1,
                                                   double* __restrict__ feats_out,
                                                   double* __restrict__ rm,
                                                   double* __restrict__ Sq) {
    const int C = 32;
    __shared__ double2 s_tab[TAB_N];   // 8.3 KB
    __shared__ double ctr[32];
    __shared__ double H1[KK][128];     // 16 KB
    __shared__ double part[4][64];     //  2 KB
    const int swz = ((blockIdx.x & 7) << 12) + (blockIdx.x >> 3);  // 32768/8 = 4096
    const int b = swz >> 9;
    const int bn = swz;
    const int tid = threadIdx.x;

    if (mask[bn] == 0) {               // block-uniform early exit (one row/block)
        if (tid == 0) { rm[bn] = 1e18; Sq[bn] = 0.0; }
        return;
    }

    for (int i = tid; i < TAB_N; i += 256) s_tab[i] = g_tab[i];
    if (tid < C) ctr[tid] = (double)x[(size_t)bn * C + tid];
    __syncthreads();

    if constexpr (UV) {
        // layer 1 via per-point projections
        const int j = tid & 127;
        const int kb = (tid >> 7) * 8;
        double tn = (double)b1[j];
        #pragma unroll 2
        for (int c = 0; c < C; ++c)
            tn += ctr[c] * ((double)W1[(C + c) * 128 + j] - (double)W1[c * 128 + j]);
        #pragma unroll
        for (int kk = 0; kk < 8; ++kk) {
            int m = idx[bn * KK + kb + kk];
            double v = U1[(size_t)(b * NN + m) * 128 + j] + tn;
            H1[kb + kk][j] = gelu64_tab(v, s_tab);
        }
    } else {
        __shared__ double edg[KK][32];
        for (int e = tid; e < KK * C; e += 256) {
            int k = e >> 5, c = e & 31;
            int m = idx[bn * KK + k];
            edg[k][c] = (double)x[((size_t)b * NN + m) * C + c] - ctr[c];
        }
        __syncthreads();
        const int j = tid & 127;
        const int kb = (tid >> 7) * 8;
        double cterm = (double)b1[j];
        #pragma unroll 2
        for (int c = 0; c < C; ++c) cterm += ctr[c] * (double)W1[(C + c) * 128 + j];
        double acc[8];
        #pragma unroll
        for (int kk = 0; kk < 8; ++kk) acc[kk] = cterm;
        #pragma unroll 2
        for (int c = 0; c < C; ++c) {
            double w = (double)W1[c * 128 + j];
            #pragma unroll
            for (int kk = 0; kk < 8; ++kk) acc[kk] += edg[kb + kk][c] * w;
        }
        #pragma unroll
        for (int kk = 0; kk < 8; ++kk) H1[kb + kk][j] = gelu64_tab(acc[kk], s_tab);
    }
    __syncthreads();

    {   // layer 2: thread -> (j = tid&63, k-group g = tid>>6 of 4);
        // each thread sums its own 4 GELU outputs -> part[g][j]
        const int j = tid & 63;
        const int g = tid >> 6;
        const int kb = g * 4;
        double acc[4];
        #pragma unroll
        for (int kk = 0; kk < 4; ++kk) acc[kk] = (double)b2[j];
        #pragma unroll 2
        for (int c = 0; c < 128; ++c) {
            double w = (double)W2[c * 64 + j];
            #pragma unroll
            for (int kk = 0; kk < 4; ++kk) acc[kk] += H1[kb + kk][c] * w;
        }
        double s = 0.0;
        #pragma unroll
        for (int kk = 0; kk < 4; ++kk) s += gelu64_tab(acc[kk], s_tab);
        part[g][j] = s;
    }
    __syncthreads();

    if (tid < 64) {   // wave 0: epilogue + fused rm/Sq (row is unmasked: sh=0)
        double s = (part[0][tid] + part[1][tid] + part[2][tid] + part[3][tid]) * 0.0625;
        feats_out[(size_t)bn * 64 + tid] = s;
        double s2 = s * s, s1 = s;
        for (int off = 32; off > 0; off >>= 1) {
            s2 += __shfl_xor(s2, off, 64);
            s1 += __shfl_xor(s1, off, 64);
        }
        if (tid == 0) { rm[bn] = s2; Sq[bn] = s1; }
    }
}

// ---------------------------------------------------------------------------
// Block-2 kNN: F=64 f64 feats, top-17 drop-first.
// 8 queries per 512-thread block; LDS-staged candidate tiles shared by all 8.
// Masked-query waves participate in staging/barriers but skip dots + select
// (their idx is never read: mlp2 zero-writes masked rows).
// ---------------------------------------------------------------------------
__global__ __launch_bounds__(512) void knn2(const double* __restrict__ feats,
                                            const int* __restrict__ mask,
                                            const double* __restrict__ rm,
                                            const double* __restrict__ Sq,
                                            int* __restrict__ idx_out) {
    __shared__ double tileT[64][65];   // [f][c], 33.3 KB
    __shared__ double qsh[8][64];      // 4 KB
    __shared__ double qrn[8], qSq[8];
    const int bid = ((blockIdx.x & 7) << 9) + (blockIdx.x >> 3);  // 4096/8 = 512
    const int b = bid >> 6;
    const int n0 = (bid & 63) * 8;
    const int tid = threadIdx.x;
    const int w = tid >> 6, lane = tid & 63;
    const int n = n0 + w;
    const int qm = mask[b * NN + n];   // wave-uniform

    {
        // For masked queries this stages stale-poison feats (finite, unused).
        qsh[w][lane] = feats[(size_t)(b * NN + n) * 64 + lane];
        if (lane == 0) { qrn[w] = rm[b * NN + n]; qSq[w] = Sq[b * NN + n]; }
    }
    __syncthreads();

    double d[8];
    #pragma unroll
    for (int t = 0; t < 8; ++t) {
        #pragma unroll
        for (int i = 0; i < 8; ++i) {
            int e = tid + 512 * i;
            int f = e & 63, c = e >> 6;
            tileT[f][c] = feats[(size_t)(b * NN + t * 64 + c) * 64 + f];
        }
        __syncthreads();
        if (qm) {
            int m = t * 64 + lane;
            double sh_m = (mask[b * NN + m] == 0) ? 999.0 : 0.0;
            double a0 = 0.0, a1 = 0.0, a2 = 0.0, a3 = 0.0;
            for (int f = 0; f < 64; f += 4) {
                a0 += qsh[w][f + 0] * tileT[f + 0][lane];
                a1 += qsh[w][f + 1] * tileT[f + 1][lane];
                a2 += qsh[w][f + 2] * tileT[f + 2][lane];
                a3 += qsh[w][f + 3] * tileT[f + 3][lane];
            }
            double dot = (a0 + a1) + (a2 + a3);
            d[t] = qrn[w] + rm[b * NN + m] - 2.0 * (dot + sh_m * qSq[w]) + 1e-5;
        }
        __syncthreads();
    }

    if (qm) {
        int* orow = idx_out + (size_t)(b * NN + n) * KK;
        SELECT_TOP17(d, lane, orow[it - 1] = bi)
    }
}

// ---------------------------------------------------------------------------
// Block-2 MLP in f32 + mean. Masked rows: write zeros, skip all compute
// (d_out is poisoned -> zeros must be written every call).
// ---------------------------------------------------------------------------
template<int UV>
__global__ __launch_bounds__(256, 2) void mlp2_f32(const double* __restrict__ feats,
                                                   const int* __restrict__ idx,
                                                   const float* __restrict__ W1,
                                                   const float* __restrict__ b1,
                                                   const float* __restrict__ W2,
                                                   const float* __restrict__ b2,
                                                   const int* __restrict__ mask,
                                                   const float* __restrict__ U2,
                                                   float* __restrict__ out) {
    const int C = 64;
    __shared__ float ctr[64];
    __shared__ float H1[KK][128];
    __shared__ float part[4][64];
    const int swz = ((blockIdx.x & 7) << 12) + (blockIdx.x >> 3);
    const int b = swz >> 9;
    const int bn = swz;
    const int tid = threadIdx.x;

    if (mask[bn] == 0) {               // block-uniform early exit
        if (tid < 64) out[(size_t)bn * 64 + tid] = 0.0f;
        return;
    }

    if (tid < C) ctr[tid] = (float)feats[(size_t)bn * C + tid];
    __syncthreads();

    if constexpr (UV) {
        const int j = tid & 127;
        const int kb = (tid >> 7) * 8;
        float tn = b1[j];
        #pragma unroll 2
        for (int c = 0; c < C; ++c)
            tn += ctr[c] * (W1[(C + c) * 128 + j] - W1[c * 128 + j]);
        #pragma unroll
        for (int kk = 0; kk < 8; ++kk) {
            int m = idx[bn * KK + kb + kk];
            H1[kb + kk][j] = gelu32(U2[(size_t)(b * NN + m) * 128 + j] + tn);
        }
    } else {
        __shared__ float edg[KK][64];
        for (int e = tid; e < KK * C; e += 256) {
            int k = e >> 6, c = e & 63;
            int m = idx[bn * KK + k];
            edg[k][c] = (float)feats[((size_t)b * NN + m) * C + c] - ctr[c];
        }
        __syncthreads();
        const int j = tid & 127;
        const int kb = (tid >> 7) * 8;
        float cterm = b1[j];
        #pragma unroll 2
        for (int c = 0; c < C; ++c) cterm += ctr[c] * W1[(C + c) * 128 + j];
        float acc[8];
        #pragma unroll
        for (int kk = 0; kk < 8; ++kk) acc[kk] = cterm;
        #pragma unroll 2
        for (int c = 0; c < C; ++c) {
            float w = W1[c * 128 + j];
            #pragma unroll
            for (int kk = 0; kk < 8; ++kk) acc[kk] += edg[kb + kk][c] * w;
        }
        #pragma unroll
        for (int kk = 0; kk < 8; ++kk) H1[kb + kk][j] = gelu32(acc[kk]);
    }
    __syncthreads();

    {   // layer 2: each thread sums its own 4 GELU outputs
        const int j = tid & 63;
        const int g = tid >> 6;
        const int kb = g * 4;
        float acc[4];
        #pragma unroll
        for (int kk = 0; kk < 4; ++kk) acc[kk] = b2[j];
        #pragma unroll 2
        for (int c = 0; c < 128; ++c) {
            float w = W2[c * 64 + j];
            #pragma unroll
            for (int kk = 0; kk < 4; ++kk) acc[kk] += H1[kb + kk][c] * w;
        }
        float s = 0.0f;
        #pragma unroll
        for (int kk = 0; kk < 4; ++kk) s += gelu32(acc[kk]);
        part[g][j] = s;
    }
    __syncthreads();

    if (tid < 64) {
        float s = (part[0][tid] + part[1][tid] + part[2][tid] + part[3][tid]) * 0.0625f;
        out[(size_t)bn * 64 + tid] = s;
    }
}

extern "C" void kernel_launch(void* const* d_in, const int* in_sizes, int n_in,
                              void* d_out, int out_size, void* d_ws, size_t ws_size,
                              hipStream_t stream) {
    const float* x      = (const float*)d_in[0];
    const float* points = (const float*)d_in[1];
    const int*   mask   = (const int*)d_in[2];
    const float* W1_0 = (const float*)d_in[3];
    const float* b1_0 = (const float*)d_in[4];
    const float* W2_0 = (const float*)d_in[5];
    const float* b2_0 = (const float*)d_in[6];
    const float* W1_1 = (const float*)d_in[7];
    const float* b1_1 = (const float*)d_in[8];
    const float* W2_1 = (const float*)d_in[9];
    const float* b2_1 = (const float*)d_in[10];

    char* ws = (char*)d_ws;
    const size_t off_tab   = 0;                      //   16 KB reserved
    const size_t off_idx   = 16384;                  //    2 MB
    const size_t off_feats = off_idx + 2097152;      // 16.8 MB
    const size_t off_rm    = off_feats + 16777216;   //  256 KB
    const size_t off_sq    = off_rm + 262144;        //  256 KB
    const size_t off_u1    = off_sq + 262144;        // 33.5 MB
    const size_t off_u2    = off_u1 + 33554432;      // 16.8 MB
    const size_t need      = off_u2 + 16777216;      // ~69.8 MB total

    double2* tab    = (double2*)(ws + off_tab);
    int*     idx    = (int*)(ws + off_idx);
    double*  feats1 = (double*)(ws + off_feats);
    double*  rm     = (double*)(ws + off_rm);
    double*  Sq     = (double*)(ws + off_sq);
    double*  U1     = (double*)(ws + off_u1);
    float*   U2     = (float*)(ws + off_u2);

    const int use_uv = (ws_size >= need) ? 1 : 0;

    build_tab<<<1, 256, 0, stream>>>(tab);
    knn1<<<BB * NN / 8, 512, 0, stream>>>(points, mask, idx);
    if (use_uv) {
        uv1<<<BB * NN / 2, 256, 0, stream>>>(x, W1_0, mask, U1);
        mlp1_f64<1><<<BB * NN, 256, 0, stream>>>(x, idx, W1_0, b1_0, W2_0, b2_0, tab,
                                                 mask, U1, feats1, rm, Sq);
        uv2<<<BB * NN / 2, 256, 0, stream>>>(feats1, W1_1, mask, U2);
        knn2<<<BB * NN / 8, 512, 0, stream>>>(feats1, mask, rm, Sq, idx);
        mlp2_f32<1><<<BB * NN, 256, 0, stream>>>(feats1, idx, W1_1, b1_1, W2_1, b2_1,
                                                 mask, U2, (float*)d_out);
    } else {
        mlp1_f64<0><<<BB * NN, 256, 0, stream>>>(x, idx, W1_0, b1_0, W2_0, b2_0, tab,
                                                 mask, U1, feats1, rm, Sq);
        knn2<<<BB * NN / 8, 512, 0, stream>>>(feats1, mask, rm, Sq, idx);
        mlp2_f32<0><<<BB * NN, 256, 0, stream>>>(feats1, idx, W1_1, b1_1, W2_1, b2_1,
                                                 mask, U2, (float*)d_out);
    }
}

// Round 9
// 698.787 us; speedup vs baseline: 10.4370x; 1.1481x over previous
//
#include <hip/hip_runtime.h>
#include <math.h>

#define BB 64
#define NN 512
#define KK 16

// ---------------------------------------------------------------------------
// GELU helpers
// ---------------------------------------------------------------------------
__device__ __forceinline__ float gelu32(float x) {
    return 0.5f * x * (1.0f + erff(x * 0.70710678118654752440f));
}

// Table-based f64 GELU: erf(z) via nearest-node cubic Taylor, h = 1/128.
// Table covers z <= 4.07 (|x| < 5.74); abs err <= ~5e-11 in range, ~3e-8 at
// the tail cutoff — invisible at the bf16 comparison and far below knn2
// rank-gap scale.
#define TAB_N 521
__device__ __forceinline__ double gelu64_tab(double x, const double2* s_tab) {
    double ax = fabs(x);
    if (ax >= 5.74) return x > 0.0 ? x : 0.0;
    double z = ax * 0.70710678118654752440;
    double u = z * 128.0;
    int i = (int)(u + 0.5);
    double zi = (double)i * (1.0 / 128.0);
    double d = z - zi;
    double2 t = s_tab[i];
    // erf(zi + d) = E + G*(d - zi*d^2 + (2*zi^2-1)/3 * d^3)
    double poly = d * (1.0 + d * (-zi + d * ((2.0 * zi * zi - 1.0) * (1.0 / 3.0))));
    double er = t.x + t.y * poly;
    double s = (x > 0.0) ? er : -er;
    return 0.5 * x * (1.0 + s);
}

__global__ void build_tab(double2* __restrict__ g_tab) {
    for (int i = threadIdx.x; i < TAB_N; i += 256) {
        double z = (double)i * (1.0 / 128.0);
        double2 e;
        e.x = erf(z);
        e.y = 1.12837916709551257390 * exp(-z * z);  // 2/sqrt(pi) * exp(-z^2)
        g_tab[i] = e;
    }
}

// ---------------------------------------------------------------------------
// Wave-local top-17 extraction from 8 register-resident candidates per lane.
// No LDS, no barriers. Tie-break: lexicographic (dist, index), identical to
// jax.lax.top_k on negated distances. Winner-removal uses compile-time
// indices only (runtime-indexed reg arrays go to scratch — rule #20).
// ---------------------------------------------------------------------------
#define SELECT_TOP17(d, lane, OUT_STMT)                                        \
    for (int it = 0; it <= KK; ++it) {                                         \
        double bd = d[0];                                                      \
        int bi = lane;                                                         \
        _Pragma("unroll")                                                      \
        for (int i = 1; i < 8; ++i) {                                          \
            int m = lane + 64 * i;                                             \
            if (d[i] < bd) { bd = d[i]; bi = m; }                              \
        }                                                                      \
        for (int off = 32; off > 0; off >>= 1) {                               \
            double od = __shfl_xor(bd, off, 64);                               \
            int    oi = __shfl_xor(bi, off, 64);                               \
            if (od < bd || (od == bd && oi < bi)) { bd = od; bi = oi; }        \
        }                                                                      \
        const int wl = bi & 63, wsl = bi >> 6;                                 \
        _Pragma("unroll")                                                      \
        for (int i = 0; i < 8; ++i)                                            \
            if (lane == wl && i == wsl) d[i] = 1e300;                          \
        if (it > 0 && lane == 0) { OUT_STMT; }                                 \
    }

// ---------------------------------------------------------------------------
// Fused block-1 kNN + U1 projection.
// Blocks [0, 4096): knn1 — F=3 points (+999 mask shift), f64, top-17
//   drop-first, 8 queries per 512-thread block, register-resident select.
// Blocks [4096, 8192): uv1 — U1[row][j] = sum_c x[row][c]*W1a[c][j] (f64),
//   8 rows per block (only launched when use_uv; masked rows skipped).
// Both precede mlp1; fusing removes one dispatch and overlaps the work.
// ---------------------------------------------------------------------------
__global__ __launch_bounds__(512) void knn1_uv1(const float* __restrict__ points,
                                                const int* __restrict__ mask,
                                                const float* __restrict__ x,
                                                const float* __restrict__ W1,
                                                int* __restrict__ idx_out,
                                                double* __restrict__ U1) {
    __shared__ double sbuf[3 * NN];    // 12 KB; uv path uses first 256 entries
    const int tid = threadIdx.x;

    if (blockIdx.x < BB * NN / 8) {
        double (*pts)[NN] = (double (*)[NN])sbuf;
        const int b = blockIdx.x >> 6;          // 64 blocks per batch
        const int n0 = (blockIdx.x & 63) * 8;
        const int w = tid >> 6, lane = tid & 63;

        for (int e = tid; e < NN; e += 512) {
            double sh = (mask[b * NN + e] == 0) ? 999.0 : 0.0;
            const float* p = points + ((size_t)b * NN + e) * 3;
            pts[0][e] = (double)p[0] + sh;
            pts[1][e] = (double)p[1] + sh;
            pts[2][e] = (double)p[2] + sh;
        }
        __syncthreads();

        const int n = n0 + w;
        if (mask[b * NN + n] == 0) return;   // wave-uniform; no barriers below
        const double q0 = pts[0][n], q1 = pts[1][n], q2 = pts[2][n];
        double d[8];
        #pragma unroll
        for (int i = 0; i < 8; ++i) {
            int m = lane + 64 * i;
            double d0 = q0 - pts[0][m], d1 = q1 - pts[1][m], d2 = q2 - pts[2][m];
            d[i] = d0 * d0 + d1 * d1 + d2 * d2;   // +1e-5 const: ordering-invariant
        }

        int* orow = idx_out + (size_t)(b * NN + n) * KK;
        SELECT_TOP17(d, lane, orow[it - 1] = bi)
    } else {
        // uv1: rows row0..row0+7
        double (*xs)[32] = (double (*)[32])sbuf;
        const int row0 = (blockIdx.x - BB * NN / 8) * 8;
        if (tid < 256) xs[tid >> 5][tid & 31] = (double)x[(size_t)row0 * 32 + tid];
        __syncthreads();
        const int j = tid & 127;
        const int rr = tid >> 7;                 // 0..3, wave-uniform (2 waves/row)
        #pragma unroll
        for (int p = 0; p < 2; ++p) {
            const int r = p * 4 + rr;
            const int row = row0 + r;
            if (mask[row] != 0) {
                double acc = 0.0;
                #pragma unroll 4
                for (int c = 0; c < 32; ++c) acc += xs[r][c] * (double)W1[c * 128 + j];
                U1[(size_t)row * 128 + j] = acc;
            }
        }
    }
}

// ---------------------------------------------------------------------------
// Block-1 MLP in f64 (table GELU) + fused rm/Sq precompute + fused U2 row
// projection for mlp2 (uv2 eliminated: the feats1 row is block-local here).
// Masked rows: rm sentinel 1e18 (masked candidates lose every unmasked
// query's top-17 with ~1e15x margin), everything else skipped.
// UV=1: layer 1 via per-point projections (in = U1[m][j] + Tn[j]).
// Register discipline: bounded unroll keeps natural VGPR demand under the
// (256,2) 128-VGPR cap (round 3: full unroll -> 9 GB scratch spill).
// ---------------------------------------------------------------------------
template<int UV>
__global__ __launch_bounds__(256, 2) void mlp1_f64(const float* __restrict__ x,
                                                   const int* __restrict__ idx,
                                                   const float* __restrict__ W1,
                                                   const float* __restrict__ b1,
                                                   const float* __restrict__ W2,
                                                   const float* __restrict__ b2,
                                                   const float* __restrict__ W1n, // W1_1 (block-2 layer 1)
                                                   const double2* __restrict__ g_tab,
                                                   const int* __restrict__ mask,
                                                   const double* __restrict__ U1,
                                                   double* __restrict__ feats_out,
                                                   double* __restrict__ rm,
                                                   double* __restrict__ Sq,
                                                   float* __restrict__ U2) {
    const int C = 32;
    __shared__ double2 s_tab[TAB_N];   // 8.3 KB
    __shared__ double ctr[32];
    __shared__ double H1[KK][128];     // 16 KB
    __shared__ double part[4][64];     //  2 KB
    __shared__ float f_row[64];        // 256 B
    const int swz = ((blockIdx.x & 7) << 12) + (blockIdx.x >> 3);  // 32768/8 = 4096
    const int b = swz >> 9;
    const int bn = swz;
    const int tid = threadIdx.x;

    if (mask[bn] == 0) {               // block-uniform early exit (one row/block)
        if (tid == 0) { rm[bn] = 1e18; Sq[bn] = 0.0; }
        return;
    }

    for (int i = tid; i < TAB_N; i += 256) s_tab[i] = g_tab[i];
    if (tid < C) ctr[tid] = (double)x[(size_t)bn * C + tid];
    __syncthreads();

    if constexpr (UV) {
        // layer 1 via per-point projections
        const int j = tid & 127;
        const int kb = (tid >> 7) * 8;
        double tn = (double)b1[j];
        #pragma unroll 4
        for (int c = 0; c < C; ++c)
            tn += ctr[c] * ((double)W1[(C + c) * 128 + j] - (double)W1[c * 128 + j]);
        #pragma unroll
        for (int kk = 0; kk < 8; ++kk) {
            int m = idx[bn * KK + kb + kk];
            double v = U1[(size_t)(b * NN + m) * 128 + j] + tn;
            H1[kb + kk][j] = gelu64_tab(v, s_tab);
        }
    } else {
        __shared__ double edg[KK][32];
        for (int e = tid; e < KK * C; e += 256) {
            int k = e >> 5, c = e & 31;
            int m = idx[bn * KK + k];
            edg[k][c] = (double)x[((size_t)b * NN + m) * C + c] - ctr[c];
        }
        __syncthreads();
        const int j = tid & 127;
        const int kb = (tid >> 7) * 8;
        double cterm = (double)b1[j];
        #pragma unroll 2
        for (int c = 0; c < C; ++c) cterm += ctr[c] * (double)W1[(C + c) * 128 + j];
        double acc[8];
        #pragma unroll
        for (int kk = 0; kk < 8; ++kk) acc[kk] = cterm;
        #pragma unroll 2
        for (int c = 0; c < C; ++c) {
            double w = (double)W1[c * 128 + j];
            #pragma unroll
            for (int kk = 0; kk < 8; ++kk) acc[kk] += edg[kb + kk][c] * w;
        }
        #pragma unroll
        for (int kk = 0; kk < 8; ++kk) H1[kb + kk][j] = gelu64_tab(acc[kk], s_tab);
    }
    __syncthreads();

    {   // layer 2: thread -> (j = tid&63, k-group g = tid>>6 of 4);
        // each thread sums its own 4 GELU outputs -> part[g][j].
        // unroll 4: 4 W2 loads in flight hides L2 latency (VGPR headroom: 40
        // at unroll 2, cap 128). Accumulation order per acc[kk] unchanged.
        const int j = tid & 63;
        const int g = tid >> 6;
        const int kb = g * 4;
        double acc[4];
        #pragma unroll
        for (int kk = 0; kk < 4; ++kk) acc[kk] = (double)b2[j];
        #pragma unroll 4
        for (int c = 0; c < 128; ++c) {
            double w = (double)W2[c * 64 + j];
            #pragma unroll
            for (int kk = 0; kk < 4; ++kk) acc[kk] += H1[kb + kk][c] * w;
        }
        double s = 0.0;
        #pragma unroll
        for (int kk = 0; kk < 4; ++kk) s += gelu64_tab(acc[kk], s_tab);
        part[g][j] = s;
    }
    __syncthreads();

    if (tid < 64) {   // wave 0: epilogue + fused rm/Sq (row is unmasked: sh=0)
        double s = (part[0][tid] + part[1][tid] + part[2][tid] + part[3][tid]) * 0.0625;
        feats_out[(size_t)bn * 64 + tid] = s;
        f_row[tid] = (float)s;
        double s2 = s * s, s1 = s;
        for (int off = 32; off > 0; off >>= 1) {
            s2 += __shfl_xor(s2, off, 64);
            s1 += __shfl_xor(s1, off, 64);
        }
        if (tid == 0) { rm[bn] = s2; Sq[bn] = s1; }
    }
    if constexpr (UV) {   // fused uv2: U2[bn][j] = sum_c f_row[c]*W1a_1[c][j]
        __syncthreads();
        if (tid < 128) {
            float acc = 0.0f;
            #pragma unroll 4
            for (int c = 0; c < 64; ++c) acc += f_row[c] * W1n[c * 128 + tid];
            U2[(size_t)bn * 128 + tid] = acc;
        }
    }
}

// ---------------------------------------------------------------------------
// Block-2 kNN: F=64 f64 feats, top-17 drop-first.
// 8 queries per 512-thread block; LDS-staged candidate tiles shared by all 8.
// Masked-query waves participate in staging/barriers but skip dots + select.
// ---------------------------------------------------------------------------
__global__ __launch_bounds__(512) void knn2(const double* __restrict__ feats,
                                            const int* __restrict__ mask,
                                            const double* __restrict__ rm,
                                            const double* __restrict__ Sq,
                                            int* __restrict__ idx_out) {
    __shared__ double tileT[64][65];   // [f][c], 33.3 KB
    __shared__ double qsh[8][64];      // 4 KB
    __shared__ double qrn[8], qSq[8];
    const int bid = ((blockIdx.x & 7) << 9) + (blockIdx.x >> 3);  // 4096/8 = 512
    const int b = bid >> 6;
    const int n0 = (bid & 63) * 8;
    const int tid = threadIdx.x;
    const int w = tid >> 6, lane = tid & 63;
    const int n = n0 + w;
    const int qm = mask[b * NN + n];   // wave-uniform

    {
        // For masked queries this stages stale-poison feats (finite, unused).
        qsh[w][lane] = feats[(size_t)(b * NN + n) * 64 + lane];
        if (lane == 0) { qrn[w] = rm[b * NN + n]; qSq[w] = Sq[b * NN + n]; }
    }
    __syncthreads();

    double d[8];
    #pragma unroll
    for (int t = 0; t < 8; ++t) {
        #pragma unroll
        for (int i = 0; i < 8; ++i) {
            int e = tid + 512 * i;
            int f = e & 63, c = e >> 6;
            tileT[f][c] = feats[(size_t)(b * NN + t * 64 + c) * 64 + f];
        }
        __syncthreads();
        if (qm) {
            int m = t * 64 + lane;
            double sh_m = (mask[b * NN + m] == 0) ? 999.0 : 0.0;
            double a0 = 0.0, a1 = 0.0, a2 = 0.0, a3 = 0.0;
            for (int f = 0; f < 64; f += 4) {
                a0 += qsh[w][f + 0] * tileT[f + 0][lane];
                a1 += qsh[w][f + 1] * tileT[f + 1][lane];
                a2 += qsh[w][f + 2] * tileT[f + 2][lane];
                a3 += qsh[w][f + 3] * tileT[f + 3][lane];
            }
            double dot = (a0 + a1) + (a2 + a3);
            d[t] = qrn[w] + rm[b * NN + m] - 2.0 * (dot + sh_m * qSq[w]) + 1e-5;
        }
        __syncthreads();
    }

    if (qm) {
        int* orow = idx_out + (size_t)(b * NN + n) * KK;
        SELECT_TOP17(d, lane, orow[it - 1] = bi)
    }
}

// ---------------------------------------------------------------------------
// Block-2 MLP in f32 + mean. Masked rows: write zeros, skip all compute
// (d_out is poisoned -> zeros must be written every call).
// ---------------------------------------------------------------------------
template<int UV>
__global__ __launch_bounds__(256, 2) void mlp2_f32(const double* __restrict__ feats,
                                                   const int* __restrict__ idx,
                                                   const float* __restrict__ W1,
                                                   const float* __restrict__ b1,
                                                   const float* __restrict__ W2,
                                                   const float* __restrict__ b2,
                                                   const int* __restrict__ mask,
                                                   const float* __restrict__ U2,
                                                   float* __restrict__ out) {
    const int C = 64;
    __shared__ float ctr[64];
    __shared__ float H1[KK][128];
    __shared__ float part[4][64];
    const int swz = ((blockIdx.x & 7) << 12) + (blockIdx.x >> 3);
    const int b = swz >> 9;
    const int bn = swz;
    const int tid = threadIdx.x;

    if (mask[bn] == 0) {               // block-uniform early exit
        if (tid < 64) out[(size_t)bn * 64 + tid] = 0.0f;
        return;
    }

    if (tid < C) ctr[tid] = (float)feats[(size_t)bn * C + tid];
    __syncthreads();

    if constexpr (UV) {
        const int j = tid & 127;
        const int kb = (tid >> 7) * 8;
        float tn = b1[j];
        #pragma unroll 4
        for (int c = 0; c < C; ++c)
            tn += ctr[c] * (W1[(C + c) * 128 + j] - W1[c * 128 + j]);
        #pragma unroll
        for (int kk = 0; kk < 8; ++kk) {
            int m = idx[bn * KK + kb + kk];
            H1[kb + kk][j] = gelu32(U2[(size_t)(b * NN + m) * 128 + j] + tn);
        }
    } else {
        __shared__ float edg[KK][64];
        for (int e = tid; e < KK * C; e += 256) {
            int k = e >> 6, c = e & 63;
            int m = idx[bn * KK + k];
            edg[k][c] = (float)feats[((size_t)b * NN + m) * C + c] - ctr[c];
        }
        __syncthreads();
        const int j = tid & 127;
        const int kb = (tid >> 7) * 8;
        float cterm = b1[j];
        #pragma unroll 2
        for (int c = 0; c < C; ++c) cterm += ctr[c] * W1[(C + c) * 128 + j];
        float acc[8];
        #pragma unroll
        for (int kk = 0; kk < 8; ++kk) acc[kk] = cterm;
        #pragma unroll 2
        for (int c = 0; c < C; ++c) {
            float w = W1[c * 128 + j];
            #pragma unroll
            for (int kk = 0; kk < 8; ++kk) acc[kk] += edg[kb + kk][c] * w;
        }
        #pragma unroll
        for (int kk = 0; kk < 8; ++kk) H1[kb + kk][j] = gelu32(acc[kk]);
    }
    __syncthreads();

    {   // layer 2: each thread sums its own 4 GELU outputs
        const int j = tid & 63;
        const int g = tid >> 6;
        const int kb = g * 4;
        float acc[4];
        #pragma unroll
        for (int kk = 0; kk < 4; ++kk) acc[kk] = b2[j];
        #pragma unroll 4
        for (int c = 0; c < 128; ++c) {
            float w = W2[c * 64 + j];
            #pragma unroll
            for (int kk = 0; kk < 4; ++kk) acc[kk] += H1[kb + kk][c] * w;
        }
        float s = 0.0f;
        #pragma unroll
        for (int kk = 0; kk < 4; ++kk) s += gelu32(acc[kk]);
        part[g][j] = s;
    }
    __syncthreads();

    if (tid < 64) {
        float s = (part[0][tid] + part[1][tid] + part[2][tid] + part[3][tid]) * 0.0625f;
        out[(size_t)bn * 64 + tid] = s;
    }
}

extern "C" void kernel_launch(void* const* d_in, const int* in_sizes, int n_in,
                              void* d_out, int out_size, void* d_ws, size_t ws_size,
                              hipStream_t stream) {
    const float* x      = (const float*)d_in[0];
    const float* points = (const float*)d_in[1];
    const int*   mask   = (const int*)d_in[2];
    const float* W1_0 = (const float*)d_in[3];
    const float* b1_0 = (const float*)d_in[4];
    const float* W2_0 = (const float*)d_in[5];
    const float* b2_0 = (const float*)d_in[6];
    const float* W1_1 = (const float*)d_in[7];
    const float* b1_1 = (const float*)d_in[8];
    const float* W2_1 = (const float*)d_in[9];
    const float* b2_1 = (const float*)d_in[10];

    char* ws = (char*)d_ws;
    const size_t off_tab   = 0;                      //   16 KB reserved
    const size_t off_idx   = 16384;                  //    2 MB
    const size_t off_feats = off_idx + 2097152;      // 16.8 MB
    const size_t off_rm    = off_feats + 16777216;   //  256 KB
    const size_t off_sq    = off_rm + 262144;        //  256 KB
    const size_t off_u1    = off_sq + 262144;        // 33.5 MB
    const size_t off_u2    = off_u1 + 33554432;      // 16.8 MB
    const size_t need      = off_u2 + 16777216;      // ~69.8 MB total

    double2* tab    = (double2*)(ws + off_tab);
    int*     idx    = (int*)(ws + off_idx);
    double*  feats1 = (double*)(ws + off_feats);
    double*  rm     = (double*)(ws + off_rm);
    double*  Sq     = (double*)(ws + off_sq);
    double*  U1     = (double*)(ws + off_u1);
    float*   U2     = (float*)(ws + off_u2);

    const int use_uv = (ws_size >= need) ? 1 : 0;
    const int knn1_blocks = BB * NN / 8;                       // 4096
    const int grid1 = knn1_blocks + (use_uv ? BB * NN / 8 : 0); // +4096 uv blocks

    build_tab<<<1, 256, 0, stream>>>(tab);
    knn1_uv1<<<grid1, 512, 0, stream>>>(points, mask, x, W1_0, idx, U1);
    if (use_uv) {
        mlp1_f64<1><<<BB * NN, 256, 0, stream>>>(x, idx, W1_0, b1_0, W2_0, b2_0, W1_1,
                                                 tab, mask, U1, feats1, rm, Sq, U2);
        knn2<<<BB * NN / 8, 512, 0, stream>>>(feats1, mask, rm, Sq, idx);
        mlp2_f32<1><<<BB * NN, 256, 0, stream>>>(feats1, idx, W1_1, b1_1, W2_1, b2_1,
                                                 mask, U2, (float*)d_out);
    } else {
        mlp1_f64<0><<<BB * NN, 256, 0, stream>>>(x, idx, W1_0, b1_0, W2_0, b2_0, W1_1,
                                                 tab, mask, U1, feats1, rm, Sq, U2);
        knn2<<<BB * NN / 8, 512, 0, stream>>>(feats1, mask, rm, Sq, idx);
        mlp2_f32<0><<<BB * NN, 256, 0, stream>>>(feats1, idx, W1_1, b1_1, W2_1, b2_1,
                                                 mask, U2, (float*)d_out);
    }
}

// Round 10
// 644.232 us; speedup vs baseline: 11.3209x; 1.0847x over previous
//
#include <hip/hip_runtime.h>
#include <math.h>

#define BB 64
#define NN 512
#define KK 16

// ---------------------------------------------------------------------------
// GELU helpers
// ---------------------------------------------------------------------------
__device__ __forceinline__ float gelu32(float x) {
    return 0.5f * x * (1.0f + erff(x * 0.70710678118654752440f));
}

// Table-based f64 GELU: erf(z) via nearest-node cubic Taylor, h = 1/64.
// Covers z <= 4.07 (|x| < 5.74); abs err ~8e-10 in range, ~3e-8 at the tail
// cutoff — ~1e7x below the knn2 rank-gap scale and invisible at bf16.
#define TAB_N 261
__device__ __forceinline__ double gelu64_tab(double x, const double2* s_tab) {
    double ax = fabs(x);
    if (ax >= 5.74) return x > 0.0 ? x : 0.0;
    double z = ax * 0.70710678118654752440;
    double u = z * 64.0;
    int i = (int)(u + 0.5);
    double zi = (double)i * (1.0 / 64.0);
    double d = z - zi;
    double2 t = s_tab[i];
    // erf(zi + d) = E + G*(d - zi*d^2 + (2*zi^2-1)/3 * d^3)
    double poly = d * (1.0 + d * (-zi + d * ((2.0 * zi * zi - 1.0) * (1.0 / 3.0))));
    double er = t.x + t.y * poly;
    double s = (x > 0.0) ? er : -er;
    return 0.5 * x * (1.0 + s);
}

__global__ void build_tab(double2* __restrict__ g_tab) {
    for (int i = threadIdx.x; i < TAB_N; i += 256) {
        double z = (double)i * (1.0 / 64.0);
        double2 e;
        e.x = erf(z);
        e.y = 1.12837916709551257390 * exp(-z * z);  // 2/sqrt(pi) * exp(-z^2)
        g_tab[i] = e;
    }
}

// ---------------------------------------------------------------------------
// Wave-local top-17 extraction from 8 register-resident candidates per lane.
// No LDS, no barriers. Tie-break: lexicographic (dist, index), identical to
// jax.lax.top_k on negated distances. Winner-removal uses compile-time
// indices only (runtime-indexed reg arrays go to scratch — rule #20).
// ---------------------------------------------------------------------------
#define SELECT_TOP17(d, lane, OUT_STMT)                                        \
    for (int it = 0; it <= KK; ++it) {                                         \
        double bd = d[0];                                                      \
        int bi = lane;                                                         \
        _Pragma("unroll")                                                      \
        for (int i = 1; i < 8; ++i) {                                          \
            int m = lane + 64 * i;                                             \
            if (d[i] < bd) { bd = d[i]; bi = m; }                              \
        }                                                                      \
        for (int off = 32; off > 0; off >>= 1) {                               \
            double od = __shfl_xor(bd, off, 64);                               \
            int    oi = __shfl_xor(bi, off, 64);                               \
            if (od < bd || (od == bd && oi < bi)) { bd = od; bi = oi; }        \
        }                                                                      \
        const int wl = bi & 63, wsl = bi >> 6;                                 \
        _Pragma("unroll")                                                      \
        for (int i = 0; i < 8; ++i)                                            \
            if (lane == wl && i == wsl) d[i] = 1e300;                          \
        if (it > 0 && lane == 0) { OUT_STMT; }                                 \
    }

// ---------------------------------------------------------------------------
// Fused block-1 kNN + U1 projection + per-batch unmasked-candidate compaction.
// Blocks [0, 4096): knn1 (8 queries per 512-thread block).
// Blocks [4096, 4096+uvb): uv1 — U1[row][j] = sum_c x[row][c]*W1a[c][j].
// Last 64 blocks: order-preserving compaction of unmasked indices per batch
// (ballot + wave prefix): cu[b][0..nU) ascending. Masked candidates are
// provably never in any unmasked query's top-17 (distance ~6.4e7 vs ~1e3),
// so knn2 only ever sees the compacted list.
// ---------------------------------------------------------------------------
__global__ __launch_bounds__(512) void knn1_uv1(const float* __restrict__ points,
                                                const int* __restrict__ mask,
                                                const float* __restrict__ x,
                                                const float* __restrict__ W1,
                                                int uvb,
                                                int* __restrict__ idx_out,
                                                double* __restrict__ U1,
                                                int* __restrict__ cu,
                                                int* __restrict__ nU) {
    __shared__ double sbuf[3 * NN];    // 12 KB
    const int tid = threadIdx.x;

    if (blockIdx.x < BB * NN / 8) {
        double (*pts)[NN] = (double (*)[NN])sbuf;
        const int b = blockIdx.x >> 6;          // 64 blocks per batch
        const int n0 = (blockIdx.x & 63) * 8;
        const int w = tid >> 6, lane = tid & 63;

        for (int e = tid; e < NN; e += 512) {
            double sh = (mask[b * NN + e] == 0) ? 999.0 : 0.0;
            const float* p = points + ((size_t)b * NN + e) * 3;
            pts[0][e] = (double)p[0] + sh;
            pts[1][e] = (double)p[1] + sh;
            pts[2][e] = (double)p[2] + sh;
        }
        __syncthreads();

        const int n = n0 + w;
        if (mask[b * NN + n] == 0) return;   // wave-uniform; no barriers below
        const double q0 = pts[0][n], q1 = pts[1][n], q2 = pts[2][n];
        double d[8];
        #pragma unroll
        for (int i = 0; i < 8; ++i) {
            int m = lane + 64 * i;
            double d0 = q0 - pts[0][m], d1 = q1 - pts[1][m], d2 = q2 - pts[2][m];
            d[i] = d0 * d0 + d1 * d1 + d2 * d2;   // +1e-5 const: ordering-invariant
        }

        int* orow = idx_out + (size_t)(b * NN + n) * KK;
        SELECT_TOP17(d, lane, orow[it - 1] = bi)
    } else if (blockIdx.x < BB * NN / 8 + uvb) {
        // uv1: rows row0..row0+7
        double (*xs)[32] = (double (*)[32])sbuf;
        const int row0 = (blockIdx.x - BB * NN / 8) * 8;
        if (tid < 256) xs[tid >> 5][tid & 31] = (double)x[(size_t)row0 * 32 + tid];
        __syncthreads();
        const int j = tid & 127;
        const int rr = tid >> 7;                 // 0..3, wave-uniform (2 waves/row)
        #pragma unroll
        for (int p = 0; p < 2; ++p) {
            const int r = p * 4 + rr;
            const int row = row0 + r;
            if (mask[row] != 0) {
                double acc = 0.0;
                #pragma unroll 4
                for (int c = 0; c < 32; ++c) acc += xs[r][c] * (double)W1[c * 128 + j];
                U1[(size_t)row * 128 + j] = acc;
            }
        }
    } else {
        // compaction: one batch per block, 512 threads = 512 candidates
        __shared__ int wcnt[8], woff[8];
        const int b = blockIdx.x - (BB * NN / 8 + uvb);
        const int w = tid >> 6, lane = tid & 63;
        const int bit = (mask[b * NN + tid] != 0) ? 1 : 0;
        unsigned long long bal = __ballot(bit);
        int pos = __popcll(bal & ((1ull << lane) - 1ull));
        if (lane == 0) wcnt[w] = __popcll(bal);
        __syncthreads();
        if (tid == 0) {
            int acc = 0;
            #pragma unroll
            for (int i = 0; i < 8; ++i) { woff[i] = acc; acc += wcnt[i]; }
            nU[b] = acc;
        }
        __syncthreads();
        if (bit) cu[b * NN + woff[w] + pos] = tid;
    }
}

// ---------------------------------------------------------------------------
// Block-1 MLP in f64 (table GELU) + fused rm precompute + fused U2 row
// projection for mlp2. Masked rows: exit immediately (masked rows are never
// candidates after compaction — rm/feats1 never read).
// UV=1: layer 1 via per-point projections (in = U1[m][j] + Tn[j]).
// Layer 2 reads H1 as double2 (ds_read_b128): 2 LDS reads per c instead of 4,
// same accumulation order (bit-identical).
// Register discipline: bounded unroll keeps natural VGPR demand under the
// (256,2) 128-VGPR cap (round 3: full unroll -> 9 GB scratch spill).
// LDS ~23.1 KB -> 6 blocks/CU.
// ---------------------------------------------------------------------------
template<int UV>
__global__ __launch_bounds__(256, 2) void mlp1_f64(const float* __restrict__ x,
                                                   const int* __restrict__ idx,
                                                   const float* __restrict__ W1,
                                                   const float* __restrict__ b1,
                                                   const float* __restrict__ W2,
                                                   const float* __restrict__ b2,
                                                   const float* __restrict__ W1n, // W1_1
                                                   const double2* __restrict__ g_tab,
                                                   const int* __restrict__ mask,
                                                   const double* __restrict__ U1,
                                                   double* __restrict__ feats_out,
                                                   double* __restrict__ rm,
                                                   float* __restrict__ U2) {
    const int C = 32;
    __shared__ double2 s_tab[TAB_N];   // 4.2 KB
    __shared__ double ctr[32];
    __shared__ double H1[KK][128];     // 16 KB
    __shared__ double part[4][64];     //  2 KB
    __shared__ float f_row[64];        // 256 B
    const int swz = ((blockIdx.x & 7) << 12) + (blockIdx.x >> 3);  // 32768/8 = 4096
    const int b = swz >> 9;
    const int bn = swz;
    const int tid = threadIdx.x;

    if (mask[bn] == 0) return;         // block-uniform; nothing downstream reads

    for (int i = tid; i < TAB_N; i += 256) s_tab[i] = g_tab[i];
    if (tid < C) ctr[tid] = (double)x[(size_t)bn * C + tid];
    __syncthreads();

    if constexpr (UV) {
        // layer 1 via per-point projections
        const int j = tid & 127;
        const int kb = (tid >> 7) * 8;
        double tn = (double)b1[j];
        #pragma unroll 4
        for (int c = 0; c < C; ++c)
            tn += ctr[c] * ((double)W1[(C + c) * 128 + j] - (double)W1[c * 128 + j]);
        #pragma unroll
        for (int kk = 0; kk < 8; ++kk) {
            int m = idx[bn * KK + kb + kk];
            double v = U1[(size_t)(b * NN + m) * 128 + j] + tn;
            H1[kb + kk][j] = gelu64_tab(v, s_tab);
        }
    } else {
        __shared__ double edg[KK][32];
        for (int e = tid; e < KK * C; e += 256) {
            int k = e >> 5, c = e & 31;
            int m = idx[bn * KK + k];
            edg[k][c] = (double)x[((size_t)b * NN + m) * C + c] - ctr[c];
        }
        __syncthreads();
        const int j = tid & 127;
        const int kb = (tid >> 7) * 8;
        double cterm = (double)b1[j];
        #pragma unroll 2
        for (int c = 0; c < C; ++c) cterm += ctr[c] * (double)W1[(C + c) * 128 + j];
        double acc[8];
        #pragma unroll
        for (int kk = 0; kk < 8; ++kk) acc[kk] = cterm;
        #pragma unroll 2
        for (int c = 0; c < C; ++c) {
            double w = (double)W1[c * 128 + j];
            #pragma unroll
            for (int kk = 0; kk < 8; ++kk) acc[kk] += edg[kb + kk][c] * w;
        }
        #pragma unroll
        for (int kk = 0; kk < 8; ++kk) H1[kb + kk][j] = gelu64_tab(acc[kk], s_tab);
    }
    __syncthreads();

    {   // layer 2: thread -> (j = tid&63, k-group g = tid>>6 of 4).
        // double2 H1 reads (b128) over c-pairs; accumulation order per acc[kk]
        // unchanged (c then c+1) -> bit-identical to scalar version.
        const int j = tid & 63;
        const int g = tid >> 6;
        const int kb = g * 4;
        double acc[4];
        #pragma unroll
        for (int kk = 0; kk < 4; ++kk) acc[kk] = (double)b2[j];
        #pragma unroll 2
        for (int c = 0; c < 128; c += 2) {
            double w0 = (double)W2[c * 64 + j];
            double w1 = (double)W2[(c + 1) * 64 + j];
            double2 h0 = *(const double2*)&H1[kb + 0][c];
            double2 h1 = *(const double2*)&H1[kb + 1][c];
            double2 h2 = *(const double2*)&H1[kb + 2][c];
            double2 h3 = *(const double2*)&H1[kb + 3][c];
            acc[0] += h0.x * w0; acc[0] += h0.y * w1;
            acc[1] += h1.x * w0; acc[1] += h1.y * w1;
            acc[2] += h2.x * w0; acc[2] += h2.y * w1;
            acc[3] += h3.x * w0; acc[3] += h3.y * w1;
        }
        double s = 0.0;
        #pragma unroll
        for (int kk = 0; kk < 4; ++kk) s += gelu64_tab(acc[kk], s_tab);
        part[g][j] = s;
    }
    __syncthreads();

    if (tid < 64) {   // wave 0: epilogue + fused rm (row is unmasked: sh=0)
        double s = (part[0][tid] + part[1][tid] + part[2][tid] + part[3][tid]) * 0.0625;
        feats_out[(size_t)bn * 64 + tid] = s;
        f_row[tid] = (float)s;
        double s2 = s * s;
        for (int off = 32; off > 0; off >>= 1) s2 += __shfl_xor(s2, off, 64);
        if (tid == 0) rm[bn] = s2;
    }
    if constexpr (UV) {   // fused uv2: U2[bn][j] = sum_c f_row[c]*W1a_1[c][j]
        __syncthreads();
        if (tid < 128) {
            float acc = 0.0f;
            #pragma unroll 4
            for (int c = 0; c < 64; ++c) acc += f_row[c] * W1n[c * 128 + tid];
            U2[(size_t)bn * 128 + tid] = acc;
        }
    }
}

// ---------------------------------------------------------------------------
// Block-2 kNN over COMPACTED unmasked candidates: F=64 f64 feats, top-17
// drop-first. 8 queries per 512-thread block; ~4 tiles instead of 8 (nU ~
// 256). All candidates unmasked -> no shift terms; distance values are
// bit-identical to the uncompacted formula (dot+0.0 == dot). Compacted order
// is ascending original index -> tie-break semantics identical.
// ---------------------------------------------------------------------------
__global__ __launch_bounds__(512) void knn2(const double* __restrict__ feats,
                                            const int* __restrict__ mask,
                                            const double* __restrict__ rm,
                                            const int* __restrict__ cu,
                                            const int* __restrict__ nU,
                                            int* __restrict__ idx_out) {
    __shared__ double tileT[64][65];   // [f][c], 33.3 KB
    __shared__ double qsh[8][64];      // 4 KB
    __shared__ double qrn[8];
    __shared__ int cI[NN];             // 2 KB
    __shared__ int s_nU;
    const int bid = ((blockIdx.x & 7) << 9) + (blockIdx.x >> 3);  // 4096/8 = 512
    const int b = bid >> 6;
    const int n0 = (bid & 63) * 8;
    const int tid = threadIdx.x;
    const int w = tid >> 6, lane = tid & 63;
    const int n = n0 + w;
    const int qm = mask[b * NN + n];   // wave-uniform

    if (tid == 0) s_nU = nU[b];
    for (int e = tid; e < NN; e += 512) cI[e] = cu[b * NN + e];
    qsh[w][lane] = feats[(size_t)(b * NN + n) * 64 + lane];
    if (lane == 0) qrn[w] = rm[b * NN + n];
    __syncthreads();

    const int nUl = s_nU;               // block-uniform
    const int ntiles = (nUl + 63) >> 6;

    double d[8];
    #pragma unroll
    for (int t = 0; t < 8; ++t) {
        d[t] = 1e300;
        if (t < ntiles) {               // block-uniform condition
            #pragma unroll
            for (int i = 0; i < 8; ++i) {
                int e = tid + 512 * i;
                int f = e & 63, c = e >> 6;
                int slot = t * 64 + c;
                if (slot < nUl)
                    tileT[f][c] = feats[(size_t)(b * NN + cI[slot]) * 64 + f];
            }
            __syncthreads();
            int slot = t * 64 + lane;
            if (qm && slot < nUl) {
                double a0 = 0.0, a1 = 0.0, a2 = 0.0, a3 = 0.0;
                for (int f = 0; f < 64; f += 4) {
                    a0 += qsh[w][f + 0] * tileT[f + 0][lane];
                    a1 += qsh[w][f + 1] * tileT[f + 1][lane];
                    a2 += qsh[w][f + 2] * tileT[f + 2][lane];
                    a3 += qsh[w][f + 3] * tileT[f + 3][lane];
                }
                double dot = (a0 + a1) + (a2 + a3);
                d[t] = qrn[w] + rm[b * NN + cI[slot]] - 2.0 * dot + 1e-5;
            }
            __syncthreads();
        }
    }

    if (qm) {
        int* orow = idx_out + (size_t)(b * NN + n) * KK;
        SELECT_TOP17(d, lane, orow[it - 1] = cI[bi])
    }
}

// ---------------------------------------------------------------------------
// Block-2 MLP in f32 + mean. Masked rows: write zeros, skip all compute.
// Layer 2 reads H1 as float4 (b128): 4 c's per read, same accumulation order.
// ---------------------------------------------------------------------------
template<int UV>
__global__ __launch_bounds__(256, 2) void mlp2_f32(const double* __restrict__ feats,
                                                   const int* __restrict__ idx,
                                                   const float* __restrict__ W1,
                                                   const float* __restrict__ b1,
                                                   const float* __restrict__ W2,
                                                   const float* __restrict__ b2,
                                                   const int* __restrict__ mask,
                                                   const float* __restrict__ U2,
                                                   float* __restrict__ out) {
    const int C = 64;
    __shared__ float ctr[64];
    __shared__ float H1[KK][128];
    __shared__ float part[4][64];
    const int swz = ((blockIdx.x & 7) << 12) + (blockIdx.x >> 3);
    const int b = swz >> 9;
    const int bn = swz;
    const int tid = threadIdx.x;

    if (mask[bn] == 0) {               // block-uniform early exit
        if (tid < 64) out[(size_t)bn * 64 + tid] = 0.0f;
        return;
    }

    if (tid < C) ctr[tid] = (float)feats[(size_t)bn * C + tid];
    __syncthreads();

    if constexpr (UV) {
        const int j = tid & 127;
        const int kb = (tid >> 7) * 8;
        float tn = b1[j];
        #pragma unroll 4
        for (int c = 0; c < C; ++c)
            tn += ctr[c] * (W1[(C + c) * 128 + j] - W1[c * 128 + j]);
        #pragma unroll
        for (int kk = 0; kk < 8; ++kk) {
            int m = idx[bn * KK + kb + kk];
            H1[kb + kk][j] = gelu32(U2[(size_t)(b * NN + m) * 128 + j] + tn);
        }
    } else {
        __shared__ float edg[KK][64];
        for (int e = tid; e < KK * C; e += 256) {
            int k = e >> 6, c = e & 63;
            int m = idx[bn * KK + k];
            edg[k][c] = (float)feats[((size_t)b * NN + m) * C + c] - ctr[c];
        }
        __syncthreads();
        const int j = tid & 127;
        const int kb = (tid >> 7) * 8;
        float cterm = b1[j];
        #pragma unroll 2
        for (int c = 0; c < C; ++c) cterm += ctr[c] * W1[(C + c) * 128 + j];
        float acc[8];
        #pragma unroll
        for (int kk = 0; kk < 8; ++kk) acc[kk] = cterm;
        #pragma unroll 2
        for (int c = 0; c < C; ++c) {
            float w = W1[c * 128 + j];
            #pragma unroll
            for (int kk = 0; kk < 8; ++kk) acc[kk] += edg[kb + kk][c] * w;
        }
        #pragma unroll
        for (int kk = 0; kk < 8; ++kk) H1[kb + kk][j] = gelu32(acc[kk]);
    }
    __syncthreads();

    {   // layer 2: float4 H1 reads over c-quads; order preserved.
        const int j = tid & 63;
        const int g = tid >> 6;
        const int kb = g * 4;
        float acc[4];
        #pragma unroll
        for (int kk = 0; kk < 4; ++kk) acc[kk] = b2[j];
        #pragma unroll 2
        for (int c = 0; c < 128; c += 4) {
            float w0 = W2[(c + 0) * 64 + j];
            float w1 = W2[(c + 1) * 64 + j];
            float w2 = W2[(c + 2) * 64 + j];
            float w3 = W2[(c + 3) * 64 + j];
            #pragma unroll
            for (int kk = 0; kk < 4; ++kk) {
                float4 h = *(const float4*)&H1[kb + kk][c];
                acc[kk] += h.x * w0; acc[kk] += h.y * w1;
                acc[kk] += h.z * w2; acc[kk] += h.w * w3;
            }
        }
        float s = 0.0f;
        #pragma unroll
        for (int kk = 0; kk < 4; ++kk) s += gelu32(acc[kk]);
        part[g][j] = s;
    }
    __syncthreads();

    if (tid < 64) {
        float s = (part[0][tid] + part[1][tid] + part[2][tid] + part[3][tid]) * 0.0625f;
        out[(size_t)bn * 64 + tid] = s;
    }
}

extern "C" void kernel_launch(void* const* d_in, const int* in_sizes, int n_in,
                              void* d_out, int out_size, void* d_ws, size_t ws_size,
                              hipStream_t stream) {
    const float* x      = (const float*)d_in[0];
    const float* points = (const float*)d_in[1];
    const int*   mask   = (const int*)d_in[2];
    const float* W1_0 = (const float*)d_in[3];
    const float* b1_0 = (const float*)d_in[4];
    const float* W2_0 = (const float*)d_in[5];
    const float* b2_0 = (const float*)d_in[6];
    const float* W1_1 = (const float*)d_in[7];
    const float* b1_1 = (const float*)d_in[8];
    const float* W2_1 = (const float*)d_in[9];
    const float* b2_1 = (const float*)d_in[10];

    char* ws = (char*)d_ws;
    const size_t off_tab   = 0;                      //   16 KB reserved
    const size_t off_idx   = 16384;                  //    2 MB
    const size_t off_feats = off_idx + 2097152;      // 16.8 MB
    const size_t off_rm    = off_feats + 16777216;   //  256 KB
    const size_t off_cu    = off_rm + 262144;        //  128 KB
    const size_t off_nu    = off_cu + 131072;        //    4 KB (64 ints + pad)
    const size_t off_u1    = off_nu + 4096;          // 33.5 MB
    const size_t off_u2    = off_u1 + 33554432;      // 16.8 MB
    const size_t need      = off_u2 + 16777216;      // ~69.6 MB total

    double2* tab    = (double2*)(ws + off_tab);
    int*     idx    = (int*)(ws + off_idx);
    double*  feats1 = (double*)(ws + off_feats);
    double*  rm     = (double*)(ws + off_rm);
    int*     cu     = (int*)(ws + off_cu);
    int*     nU     = (int*)(ws + off_nu);
    double*  U1     = (double*)(ws + off_u1);
    float*   U2     = (float*)(ws + off_u2);

    const int use_uv = (ws_size >= need) ? 1 : 0;
    const int uvb = use_uv ? BB * NN / 8 : 0;
    const int grid1 = BB * NN / 8 + uvb + BB;   // knn + uv + compaction

    build_tab<<<1, 256, 0, stream>>>(tab);
    knn1_uv1<<<grid1, 512, 0, stream>>>(points, mask, x, W1_0, uvb, idx, U1, cu, nU);
    if (use_uv) {
        mlp1_f64<1><<<BB * NN, 256, 0, stream>>>(x, idx, W1_0, b1_0, W2_0, b2_0, W1_1,
                                                 tab, mask, U1, feats1, rm, U2);
        knn2<<<BB * NN / 8, 512, 0, stream>>>(feats1, mask, rm, cu, nU, idx);
        mlp2_f32<1><<<BB * NN, 256, 0, stream>>>(feats1, idx, W1_1, b1_1, W2_1, b2_1,
                                                 mask, U2, (float*)d_out);
    } else {
        mlp1_f64<0><<<BB * NN, 256, 0, stream>>>(x, idx, W1_0, b1_0, W2_0, b2_0, W1_1,
                                                 tab, mask, U1, feats1, rm, U2);
        knn2<<<BB * NN / 8, 512, 0, stream>>>(feats1, mask, rm, cu, nU, idx);
        mlp2_f32<0><<<BB * NN, 256, 0, stream>>>(feats1, idx, W1_1, b1_1, W2_1, b2_1,
                                                 mask, U2, (float*)d_out);
    }
}